// Round 4
// baseline (305.113 us; speedup 1.0000x reference)
//
#include <hip/hip_runtime.h>

#define G 128

__device__ __forceinline__ float dot4(float4 a, float4 b) {
    return a.x * b.x + a.y * b.y + a.z * b.z + a.w * b.w;
}

// ---------------------------------------------------------------------------
// Kernel A: fused conv1 (3x3x3, 1->16, SAME) + relu + m0-mask + 2x2x2 maxpool.
// Conv region 16(x)x16(y)x8(z) per block, 256 threads, 2048 blocks.
// Staging tile 18x18x10; occ+x loaded UNCONDITIONALLY & INDEPENDENTLY with
// the loop fully unrolled (26 loads in flight -> one HBM round-trip).
// List build (ballot-compacted active centers) is merged into staging.
// Compute: dense 27x16 FMA per active center on consecutive lanes; pool via
// atomicMax into stride-17 LDS tile. LDS ~35KB -> 4 blocks/CU.
// ---------------------------------------------------------------------------
__global__ __launch_bounds__(256)
void k_conv1_pool(const float* __restrict__ x, const int* __restrict__ occ,
                  const float* __restrict__ W1,
                  float* __restrict__ h1p, float* __restrict__ m1)
{
    __shared__ float          sx[10 * 18 * 18];      // [z][y][x]
    __shared__ unsigned short lst[2048];
    __shared__ int            tile[256 * 17];        // [parent][17] float bits
    __shared__ int            pflag[256];
    __shared__ int            cnt;

    const int bx = blockIdx.x, by = blockIdx.y;
    const int b  = blockIdx.z >> 4, bz = blockIdx.z & 15;
    const int tid  = threadIdx.x;
    const int lane = tid & 63;

    for (int i = tid; i < 256 * 17; i += 256) tile[i] = 0;
    pflag[tid] = 0;
    if (tid == 0) cnt = 0;
    __syncthreads();

    const int z0 = bz * 8 - 1, y0 = by * 16 - 1, x0 = bx * 16 - 1;
    const int base_b = b * G * G * G;

    #pragma unroll
    for (int it = 0; it < 13; ++it) {
        int i = it * 256 + tid;
        bool vi = (i < 3240);
        int lz = i / 324, r = i - lz * 324;
        int ly = r / 18,  lx = r - ly * 18;
        int gz = z0 + lz, gy = y0 + ly, gx = x0 + lx;
        bool inb = vi && (unsigned)gz < 128u && (unsigned)gy < 128u &&
                   (unsigned)gx < 128u;
        int gi = base_b + (gz * G + gy) * G + gx;
        int oc = 1; float xv = 0.f;
        if (inb) {                       // two INDEPENDENT loads, both issue
            oc = occ[gi];
            xv = x[gi];
        }
        bool mm = inb && (oc == 0);
        if (vi) sx[i] = mm ? xv : 0.f;
        bool flag = mm && lz >= 1 && lz <= 8 && ly >= 1 && ly <= 16 &&
                    lx >= 1 && lx <= 16;
        unsigned long long mb = __ballot(flag);
        if (mb) {
            int wbase = 0;
            if (lane == 0) wbase = atomicAdd(&cnt, __popcll(mb));
            wbase = __shfl(wbase, 0);
            if (flag) {
                int cz = lz - 1, cy = ly - 1, cx = lx - 1;
                int lofs = __popcll(mb & ((1ull << lane) - 1ull));
                lst[wbase + lofs] = (unsigned short)((cz << 8) | (cy << 4) | cx);
                pflag[((cz >> 1) << 6) | ((cy >> 1) << 3) | (cx >> 1)] = 1;
            }
        }
    }
    __syncthreads();

    const int n = cnt;                   // ~205 avg of 2048 centers
    for (int i = tid; i < n; i += 256) {
        int e = lst[i];
        int cz = e >> 8, cy = (e >> 4) & 15, cx = e & 15;
        int tb = cz * 324 + cy * 18 + cx;
        float acc[16];
        #pragma unroll
        for (int c = 0; c < 16; ++c) acc[c] = 0.f;
        #pragma unroll
        for (int kz = 0; kz < 3; ++kz)
        #pragma unroll
        for (int ky = 0; ky < 3; ++ky)
        #pragma unroll
        for (int kx = 0; kx < 3; ++kx) {
            float v = sx[tb + kz * 324 + ky * 18 + kx];
            const float* w = &W1[((kz * 3 + ky) * 3 + kx) * 16];
            #pragma unroll
            for (int c = 0; c < 16; ++c) acc[c] += v * w[c];
        }
        int pb = (((cz >> 1) << 6) | ((cy >> 1) << 3) | (cx >> 1)) * 17;
        #pragma unroll
        for (int c = 0; c < 16; ++c) {
            float rr = acc[c] > 0.f ? acc[c] : 0.f;
            if (rr > 0.f) atomicMax(&tile[pb + c], __float_as_int(rr));
        }
    }
    __syncthreads();

    // writeback: thread = parent (czh = tid>>6 in [0,3], cyh, cxh in [0,7])
    const int cxh = tid & 7, cyh = (tid >> 3) & 7, czh = tid >> 6;
    const int pz = bz * 4 + czh, py = by * 8 + cyh, px = bx * 8 + cxh;
    const int vidx = ((b * 64 + pz) * 64 + py) * 64 + px;
    const int tb = tid * 17;
    float4* o = (float4*)&h1p[vidx * 16];
    o[0] = make_float4(__int_as_float(tile[tb + 0]),  __int_as_float(tile[tb + 1]),
                       __int_as_float(tile[tb + 2]),  __int_as_float(tile[tb + 3]));
    o[1] = make_float4(__int_as_float(tile[tb + 4]),  __int_as_float(tile[tb + 5]),
                       __int_as_float(tile[tb + 6]),  __int_as_float(tile[tb + 7]));
    o[2] = make_float4(__int_as_float(tile[tb + 8]),  __int_as_float(tile[tb + 9]),
                       __int_as_float(tile[tb + 10]), __int_as_float(tile[tb + 11]));
    o[3] = make_float4(__int_as_float(tile[tb + 12]), __int_as_float(tile[tb + 13]),
                       __int_as_float(tile[tb + 14]), __int_as_float(tile[tb + 15]));
    m1[vidx] = pflag[tid] ? 1.f : 0.f;
}

// ---------------------------------------------------------------------------
// Kernel B: fused conv2 (3x3x3, 16->4, SAME at 64^3) + relu + m1-mask + pool.
// 256 threads/block, conv region 8^3; thread = 2 x-adjacent conv voxels.
// Channels split into FOUR passes of 4 (tile = 1300 float4 = 20.8KB).
// Unconditional unrolled staging. Weights are wave-uniform -> scalar loads.
// Pool via 2x shfl_xor + in-register x-max. Grid (8,8,16).
// ---------------------------------------------------------------------------
__global__ __launch_bounds__(256)
void k_conv2_pool(const float* __restrict__ h1p, const float* __restrict__ m1,
                  const float* __restrict__ W2,
                  float* __restrict__ h2, float* __restrict__ m2)
{
    __shared__ float4 tile[1300];   // 20.8 KB: idx = z*130 + y*13 + x

    const int bx = blockIdx.x, by = blockIdx.y;
    const int b  = blockIdx.z >> 3, bz = blockIdx.z & 7;
    const int tid = threadIdx.x;

    const int dy = tid & 1, dz = (tid >> 1) & 1;
    const int qx = (tid >> 2) & 3, Y = (tid >> 4) & 3, Z = (tid >> 6) & 3;
    const int cx0 = 2 * qx, cy = 2 * Y + dy, cz = 2 * Z + dz;

    const int z0 = bz * 8 - 1, y0 = by * 16 - 1 + 0, x0 = bx * 8 - 1;
    // NOTE: region is 8^3; y0 must match: by indexes 8-wide y
    const int y0r = by * 8 - 1;

    float4 acc0 = make_float4(0.f, 0.f, 0.f, 0.f);
    float4 acc1 = make_float4(0.f, 0.f, 0.f, 0.f);

    for (int h = 0; h < 4; ++h) {
        if (h) __syncthreads();
        #pragma unroll
        for (int it = 0; it < 4; ++it) {
            int v = it * 256 + tid;
            bool vv = v < 1000;
            int z = v / 100, r = v - z * 100, y = r / 10, xx = r - y * 10;
            int gz = z0 + z, gy = y0r + y, gx = x0 + xx;
            float4 a = make_float4(0.f, 0.f, 0.f, 0.f);
            if (vv && (unsigned)gz < 64u && (unsigned)gy < 64u && (unsigned)gx < 64u)
                a = ((const float4*)&h1p[(((b * 64 + gz) * 64 + gy) * 64 + gx) * 16])[h];
            if (vv) tile[z * 130 + y * 13 + xx] = a;
        }
        __syncthreads();

        #pragma unroll
        for (int kz = 0; kz < 3; ++kz)
        #pragma unroll
        for (int ky = 0; ky < 3; ++ky) {
            const int rb = (cz + kz) * 130 + (cy + ky) * 13 + cx0;
            const float* wrow = &W2[((kz * 3 + ky) * 3) * 64 + h * 16];
            #pragma unroll
            for (int xi = 0; xi < 4; ++xi) {
                float4 v0 = tile[rb + xi];
                #pragma unroll
                for (int j = 0; j < 2; ++j) {
                    int kx = xi - j;
                    if (kx < 0 || kx > 2) continue;
                    const float* w = wrow + kx * 64;   // [ci_local*4 + co]
                    float4 w0 = *(const float4*)(w);
                    float4 w1 = *(const float4*)(w + 4);
                    float4 w2 = *(const float4*)(w + 8);
                    float4 w3 = *(const float4*)(w + 12);
                    float4* acc = j ? &acc1 : &acc0;
                    acc->x += v0.x * w0.x + v0.y * w1.x + v0.z * w2.x + v0.w * w3.x;
                    acc->y += v0.x * w0.y + v0.y * w1.y + v0.z * w2.y + v0.w * w3.y;
                    acc->z += v0.x * w0.z + v0.y * w1.z + v0.z * w2.z + v0.w * w3.z;
                    acc->w += v0.x * w0.w + v0.y * w1.w + v0.z * w2.w + v0.w * w3.w;
                }
            }
        }
    }

    const int gcz = bz * 8 + cz, gcy = by * 8 + cy, gcx = bx * 8 + cx0;
    const float mv0 = m1[((b * 64 + gcz) * 64 + gcy) * 64 + gcx];
    const float mv1 = m1[((b * 64 + gcz) * 64 + gcy) * 64 + gcx + 1];
    float m = fmaxf(mv0, mv1);
    float r0 = fmaxf(fmaxf(acc0.x, 0.f) * mv0, fmaxf(acc1.x, 0.f) * mv1);
    float r1 = fmaxf(fmaxf(acc0.y, 0.f) * mv0, fmaxf(acc1.y, 0.f) * mv1);
    float r2 = fmaxf(fmaxf(acc0.z, 0.f) * mv0, fmaxf(acc1.z, 0.f) * mv1);
    float r3 = fmaxf(fmaxf(acc0.w, 0.f) * mv0, fmaxf(acc1.w, 0.f) * mv1);

    #pragma unroll
    for (int mask = 1; mask <= 2; mask <<= 1) {
        r0 = fmaxf(r0, __shfl_xor(r0, mask));
        r1 = fmaxf(r1, __shfl_xor(r1, mask));
        r2 = fmaxf(r2, __shfl_xor(r2, mask));
        r3 = fmaxf(r3, __shfl_xor(r3, mask));
        m  = fmaxf(m,  __shfl_xor(m,  mask));
    }
    if ((tid & 3) == 0) {
        int pz = bz * 4 + Z, py = by * 4 + Y, px = bx * 4 + qx;
        int oidx = ((b * 32 + pz) * 32 + py) * 32 + px;
        *(float4*)&h2[oidx * 4] = make_float4(r0, r1, r2, r3);
        m2[oidx] = m;
    }
}

// ---------------------------------------------------------------------------
// Kernel C: fused decoder. tconv1(2^3 s2, 4->16)+relu then tconv2+sigmoid,
// masked by m2. JAX conv_transpose flips the kernel: out[2i+a]=x[i]*W[1-a].
// Weights staged to LDS once per block, read as broadcast ds_read_b128
// (kills the 256 per-thread global weight loads). Thread = (parent, a, bb).
// ---------------------------------------------------------------------------
__global__ __launch_bounds__(256)
void k_decoder(const float* __restrict__ h2, const float* __restrict__ m2,
               const float* __restrict__ Wt1, const float* __restrict__ Wt2,
               float* __restrict__ out)
{
    __shared__ float4 w1s[256];   // Wt1: 1024 floats
    __shared__ float4 w2s[32];    // Wt2: 128 floats

    const int tid = threadIdx.x;
    w1s[tid] = ((const float4*)Wt1)[tid];
    if (tid < 32) w2s[tid] = ((const float4*)Wt2)[tid];
    __syncthreads();

    const int T  = blockIdx.x * 256 + tid;          // 0..262143
    const int px = T & 31;
    const int a  = (T >> 5) & 1;
    const int bb = (T >> 6) & 1;
    const int py = (T >> 7) & 31;
    const int pz = (T >> 12) & 31;
    const int b  = T >> 17;
    const int pidx = ((b * 32 + pz) * 32 + py) * 32 + px;

    const float m = m2[pidx];
    const float4 hv = *(const float4*)&h2[pidx * 4];

    // tconv1: th1[2pz+a][2py+bb][2px+c][ch], weights row Wt1[1-a][1-bb][1-c]
    const int b0q = ((((1 - a) * 2 + (1 - bb)) * 2) + 1) * 16;  // c=0 -> kc=1
    const int b1q = ((((1 - a) * 2 + (1 - bb)) * 2) + 0) * 16;  // c=1 -> kc=0
    float4 t0q[4], t1q[4];
    #pragma unroll
    for (int q = 0; q < 4; ++q) {
        float4 a0 = w1s[b0q + q],      a1 = w1s[b0q + 4 + q];
        float4 a2 = w1s[b0q + 8 + q],  a3 = w1s[b0q + 12 + q];
        float4 c0 = w1s[b1q + q],      c1 = w1s[b1q + 4 + q];
        float4 c2 = w1s[b1q + 8 + q],  c3 = w1s[b1q + 12 + q];
        float4 s0, s1;
        s0.x = hv.x * a0.x + hv.y * a1.x + hv.z * a2.x + hv.w * a3.x;
        s0.y = hv.x * a0.y + hv.y * a1.y + hv.z * a2.y + hv.w * a3.y;
        s0.z = hv.x * a0.z + hv.y * a1.z + hv.z * a2.z + hv.w * a3.z;
        s0.w = hv.x * a0.w + hv.y * a1.w + hv.z * a2.w + hv.w * a3.w;
        s1.x = hv.x * c0.x + hv.y * c1.x + hv.z * c2.x + hv.w * c3.x;
        s1.y = hv.x * c0.y + hv.y * c1.y + hv.z * c2.y + hv.w * c3.y;
        s1.z = hv.x * c0.z + hv.y * c1.z + hv.z * c2.z + hv.w * c3.z;
        s1.w = hv.x * c0.w + hv.y * c1.w + hv.z * c2.w + hv.w * c3.w;
        t0q[q] = make_float4(fmaxf(s0.x, 0.f), fmaxf(s0.y, 0.f),
                             fmaxf(s0.z, 0.f), fmaxf(s0.w, 0.f));
        t1q[q] = make_float4(fmaxf(s1.x, 0.f), fmaxf(s1.y, 0.f),
                             fmaxf(s1.z, 0.f), fmaxf(s1.w, 0.f));
    }

    #pragma unroll
    for (int e = 0; e < 2; ++e) {
        #pragma unroll
        for (int f = 0; f < 2; ++f) {
            const int d  = 4 * pz + 2 * a + e;
            const int hh = 4 * py + 2 * bb + f;
            const int be = ((1 - e) * 2 + (1 - f)) * 2;
            const float4* wg0 = &w2s[(be + 1) * 4];   // g=0 -> kg=1
            const float4* wg1 = &w2s[(be + 0) * 4];   // g=1 -> kg=0
            float s00 = dot4(t0q[0], wg0[0]) + dot4(t0q[1], wg0[1])
                      + dot4(t0q[2], wg0[2]) + dot4(t0q[3], wg0[3]);
            float s01 = dot4(t0q[0], wg1[0]) + dot4(t0q[1], wg1[1])
                      + dot4(t0q[2], wg1[2]) + dot4(t0q[3], wg1[3]);
            float s10 = dot4(t1q[0], wg0[0]) + dot4(t1q[1], wg0[1])
                      + dot4(t1q[2], wg0[2]) + dot4(t1q[3], wg0[3]);
            float s11 = dot4(t1q[0], wg1[0]) + dot4(t1q[1], wg1[1])
                      + dot4(t1q[2], wg1[2]) + dot4(t1q[3], wg1[3]);
            float4 o;
            o.x = m / (1.f + __expf(-s00));
            o.y = m / (1.f + __expf(-s01));
            o.z = m / (1.f + __expf(-s10));
            o.w = m / (1.f + __expf(-s11));
            *(float4*)&out[((b * G + d) * G + hh) * G + 4 * px] = o;
        }
    }
}

extern "C" void kernel_launch(void* const* d_in, const int* in_sizes, int n_in,
                              void* d_out, int out_size, void* d_ws, size_t ws_size,
                              hipStream_t stream) {
    (void)in_sizes; (void)n_in; (void)out_size; (void)ws_size;
    const float* x   = (const float*)d_in[0];
    const float* W1  = (const float*)d_in[1];
    const float* W2  = (const float*)d_in[2];
    const float* Wt1 = (const float*)d_in[3];
    const float* Wt2 = (const float*)d_in[4];
    const int*   occ = (const int*)d_in[5];
    float* out = (float*)d_out;

    float* ws  = (float*)d_ws;
    float* h1p = ws;                          // 2*64^3*16 floats
    float* m1  = h1p + 2 * 64 * 64 * 64 * 16; // 2*64^3
    float* h2  = m1  + 2 * 64 * 64 * 64;      // 2*32^3*4
    float* m2v = h2  + 2 * 32 * 32 * 32 * 4;  // 2*32^3

    k_conv1_pool<<<dim3(8, 8, 32), dim3(256), 0, stream>>>(x, occ, W1, h1p, m1);
    k_conv2_pool<<<dim3(8, 8, 16), dim3(256), 0, stream>>>(h1p, m1, W2, h2, m2v);
    k_decoder<<<dim3(1024), dim3(256), 0, stream>>>(h2, m2v, Wt1, Wt2, out);
}

// Round 5
// 231.031 us; speedup vs baseline: 1.3207x; 1.3207x over previous
//
#include <hip/hip_runtime.h>
#include <hip/hip_fp16.h>

#define G 128

union H8 { uint4 u; __half h[8]; __half2 h2[4]; };

// ---------------------------------------------------------------------------
// Kernel A: fused conv1 (3x3x3, 1->16, SAME) + relu + m0-mask + 2x2x2 maxpool.
// Lean compaction:
//  - staging: thread = (y,x) column of the 18^3 tile, z-loop with 1 mad/step,
//    no divides, loads unconditional-per-column; builds 16-bit active-z mask
//    in a register.
//  - list: ONE prefix-scan over per-column popcounts (shfl scan + 8 partials)
//  - m1: derived from stored column masks (no atomics)
//  - weights: global with uniform indices -> scalar loads (constant cache)
//  - pool: atomicMax into stride-17 LDS tile (conflicts measured negligible)
// Block 512, grid (8,8,16) = 1024 blocks, conv region 16^3. h1p stored fp16.
// ---------------------------------------------------------------------------
__global__ __launch_bounds__(512)
void k_conv1_pool(const float* __restrict__ x, const int* __restrict__ occ,
                  const float* __restrict__ W1,
                  __half* __restrict__ h1p, float* __restrict__ m1)
{
    __shared__ float          sx[18 * 18 * 18];   // [z][y*18+x]
    __shared__ int            tile[512 * 17];     // [parent][17], float bits
    __shared__ unsigned short lst[4096];
    __shared__ unsigned short am[16 * 16];        // per interior column active-z mask
    __shared__ int            wsum[8];

    const int bx = blockIdx.x, by = blockIdx.y;
    const int b  = blockIdx.z >> 3, bz = blockIdx.z & 7;
    const int tid  = threadIdx.x;
    const int lane = tid & 63, wid = tid >> 6;

    for (int i = tid; i < 512 * 17; i += 512) tile[i] = 0;

    const int z0 = bz * 16 - 1, y0 = by * 16 - 1, x0 = bx * 16 - 1;
    const int base_b = b * G * G * G;

    const int ly = tid / 18, lx = tid - ly * 18;          // one divide, total
    unsigned amask = 0;
    if (tid < 324) {
        const int gy = y0 + ly, gx = x0 + lx;
        const bool yxin = (unsigned)gy < 128u && (unsigned)gx < 128u;
        const int  yxoff = gy * G + gx;
        const bool interior = (ly >= 1 && ly <= 16 && lx >= 1 && lx <= 16);
        #pragma unroll
        for (int lz = 0; lz < 18; ++lz) {
            int  gz  = z0 + lz;
            bool inb = yxin && (unsigned)gz < 128u;
            int  gi  = base_b + gz * (G * G) + yxoff;
            int  oc = 1; float xv = 0.f;
            if (inb) { oc = occ[gi]; xv = x[gi]; }        // independent loads
            bool mm = inb && (oc == 0);
            sx[lz * 324 + tid] = mm ? xv : 0.f;
            if (mm && interior && lz >= 1 && lz <= 16) amask |= 1u << (lz - 1);
        }
        if (interior) am[(ly - 1) * 16 + (lx - 1)] = (unsigned short)amask;
    }

    // ---- single prefix-scan list build ----
    const int cntv = __popc(amask);
    int s = cntv;
    #pragma unroll
    for (int d = 1; d < 64; d <<= 1) {
        int t = __shfl_up(s, d);
        if (lane >= d) s += t;
    }
    if (lane == 63) wsum[wid] = s;
    __syncthreads();
    int basek = 0, tot = 0;
    #pragma unroll
    for (int w = 0; w < 8; ++w) {
        int v = wsum[w];
        if (w < wid) basek += v;
        tot += v;
    }
    int k = basek + s - cntv;                    // exclusive offset
    unsigned mmk = amask;
    while (mmk) {
        int i = __ffs(mmk) - 1; mmk &= mmk - 1;
        lst[k++] = (unsigned short)((i << 8) | ((ly - 1) << 4) | (lx - 1));
    }
    __syncthreads();

    // ---- dense compute on compacted centers ----
    const int n = tot;
    for (int i = tid; i < n; i += 512) {
        int e = lst[i];
        int cz = e >> 8, cy = (e >> 4) & 15, cx = e & 15;
        int tb = cz * 324 + cy * 18 + cx;
        float acc[16];
        #pragma unroll
        for (int c = 0; c < 16; ++c) acc[c] = 0.f;
        #pragma unroll
        for (int kz = 0; kz < 3; ++kz)
        #pragma unroll
        for (int ky = 0; ky < 3; ++ky)
        #pragma unroll
        for (int kx = 0; kx < 3; ++kx) {
            float v = sx[tb + kz * 324 + ky * 18 + kx];
            const float* w = &W1[((kz * 3 + ky) * 3 + kx) * 16];  // uniform -> s_load
            #pragma unroll
            for (int c = 0; c < 16; ++c) acc[c] += v * w[c];
        }
        int pb = (((cz >> 1) << 6) | ((cy >> 1) << 3) | (cx >> 1)) * 17;
        #pragma unroll
        for (int c = 0; c < 16; ++c) {
            float r = acc[c] > 0.f ? acc[c] : 0.f;
            if (r > 0.f) atomicMax(&tile[pb + c], __float_as_int(r));
        }
    }
    __syncthreads();

    // ---- writeback (fp16) + m1 from column masks ----
    const int cxh = tid & 7, cyh = (tid >> 3) & 7, czh = tid >> 6;
    const int pz = bz * 8 + czh, py = by * 8 + cyh, px = bx * 8 + cxh;
    const int vidx = ((b * 64 + pz) * 64 + py) * 64 + px;
    const int tb = tid * 17;
    H8 p0, p1;
    #pragma unroll
    for (int c = 0; c < 8; ++c) p0.h[c] = __float2half(__int_as_float(tile[tb + c]));
    #pragma unroll
    for (int c = 0; c < 8; ++c) p1.h[c] = __float2half(__int_as_float(tile[tb + 8 + c]));
    uint4* o = (uint4*)&h1p[(size_t)vidx * 16];
    o[0] = p0.u;
    o[1] = p1.u;
    unsigned mb = am[(2 * cyh) * 16 + 2 * cxh]     | am[(2 * cyh) * 16 + 2 * cxh + 1]
                | am[(2 * cyh + 1) * 16 + 2 * cxh] | am[(2 * cyh + 1) * 16 + 2 * cxh + 1];
    m1[vidx] = ((mb >> (2 * czh)) & 3u) ? 1.f : 0.f;
}

// ---------------------------------------------------------------------------
// Kernel B: fused conv2 (3x3x3, 16->4, SAME at 64^3) + relu + m1-mask + pool.
// h1p input is fp16 (half the fetch). 256 thr, conv region 8^3, thread = 2
// x-adjacent conv voxels. Channels in TWO passes of 8 (tile of uint4 = 8
// halfs per voxel, 17.6 KB -> full occupancy). Tap row cached in registers
// per (kz,ky); weights uniform-indexed (scalar loads). Grid (8,8,16).
// ---------------------------------------------------------------------------
__global__ __launch_bounds__(256)
void k_conv2_pool(const __half* __restrict__ h1p, const float* __restrict__ m1,
                  const float* __restrict__ W2,
                  float* __restrict__ h2, float* __restrict__ m2)
{
    __shared__ uint4 tile[10 * 110];   // idx = z*110 + y*11 + x

    const int bx = blockIdx.x, by = blockIdx.y;
    const int b  = blockIdx.z >> 3, bz = blockIdx.z & 7;
    const int tid = threadIdx.x;

    const int dy = tid & 1, dz = (tid >> 1) & 1;
    const int qx = (tid >> 2) & 3, Y = (tid >> 4) & 3, Z = (tid >> 6) & 3;
    const int cx0 = 2 * qx, cy = 2 * Y + dy, cz = 2 * Z + dz;

    const int z0 = bz * 8 - 1, y0 = by * 8 - 1, x0 = bx * 8 - 1;

    float4 acc0 = make_float4(0.f, 0.f, 0.f, 0.f);
    float4 acc1 = make_float4(0.f, 0.f, 0.f, 0.f);

    for (int h = 0; h < 2; ++h) {
        if (h) __syncthreads();
        #pragma unroll
        for (int it = 0; it < 4; ++it) {
            int v = it * 256 + tid;
            if (v < 1000) {
                int z = v / 100, r = v - z * 100, y = r / 10, xx = r - y * 10;
                int gz = z0 + z, gy = y0 + y, gx = x0 + xx;
                uint4 a = make_uint4(0u, 0u, 0u, 0u);
                if ((unsigned)gz < 64u && (unsigned)gy < 64u && (unsigned)gx < 64u)
                    a = ((const uint4*)&h1p[(size_t)(((b * 64 + gz) * 64 + gy) * 64 + gx) * 16])[h];
                tile[z * 110 + y * 11 + xx] = a;
            }
        }
        __syncthreads();

        #pragma unroll
        for (int kz = 0; kz < 3; ++kz)
        #pragma unroll
        for (int ky = 0; ky < 3; ++ky) {
            const int rb = (cz + kz) * 110 + (cy + ky) * 11 + cx0;
            float f[4][8];
            #pragma unroll
            for (int xi = 0; xi < 4; ++xi) {
                H8 hh; hh.u = tile[rb + xi];
                #pragma unroll
                for (int q = 0; q < 4; ++q) {
                    float2 f2 = __half22float2(hh.h2[q]);
                    f[xi][2 * q]     = f2.x;
                    f[xi][2 * q + 1] = f2.y;
                }
            }
            const float* wt = &W2[((kz * 3 + ky) * 3) * 64 + h * 32];
            #pragma unroll
            for (int kx = 0; kx < 3; ++kx) {
                const float* w = wt + kx * 64;   // uniform -> scalar loads
                #pragma unroll
                for (int j = 0; j < 2; ++j) {
                    const float* ff = f[kx + j];
                    float4* acc = j ? &acc1 : &acc0;
                    #pragma unroll
                    for (int ci = 0; ci < 8; ++ci) {
                        float vv = ff[ci];
                        acc->x += vv * w[ci * 4 + 0];
                        acc->y += vv * w[ci * 4 + 1];
                        acc->z += vv * w[ci * 4 + 2];
                        acc->w += vv * w[ci * 4 + 3];
                    }
                }
            }
        }
    }

    const int gcz = bz * 8 + cz, gcy = by * 8 + cy, gcx = bx * 8 + cx0;
    const float mv0 = m1[((b * 64 + gcz) * 64 + gcy) * 64 + gcx];
    const float mv1 = m1[((b * 64 + gcz) * 64 + gcy) * 64 + gcx + 1];
    float m = fmaxf(mv0, mv1);
    float r0 = fmaxf(fmaxf(acc0.x, 0.f) * mv0, fmaxf(acc1.x, 0.f) * mv1);
    float r1 = fmaxf(fmaxf(acc0.y, 0.f) * mv0, fmaxf(acc1.y, 0.f) * mv1);
    float r2 = fmaxf(fmaxf(acc0.z, 0.f) * mv0, fmaxf(acc1.z, 0.f) * mv1);
    float r3 = fmaxf(fmaxf(acc0.w, 0.f) * mv0, fmaxf(acc1.w, 0.f) * mv1);

    #pragma unroll
    for (int mask = 1; mask <= 2; mask <<= 1) {
        r0 = fmaxf(r0, __shfl_xor(r0, mask));
        r1 = fmaxf(r1, __shfl_xor(r1, mask));
        r2 = fmaxf(r2, __shfl_xor(r2, mask));
        r3 = fmaxf(r3, __shfl_xor(r3, mask));
        m  = fmaxf(m,  __shfl_xor(m,  mask));
    }
    if ((tid & 3) == 0) {
        int pz = bz * 4 + Z, py = by * 4 + Y, px = bx * 4 + qx;
        int oidx = ((b * 32 + pz) * 32 + py) * 32 + px;
        *(float4*)&h2[oidx * 4] = make_float4(r0, r1, r2, r3);
        m2[oidx] = m;
    }
}

__device__ __forceinline__ float dot4(float4 a, float4 b) {
    return a.x * b.x + a.y * b.y + a.z * b.z + a.w * b.w;
}

// ---------------------------------------------------------------------------
// Kernel C: fused decoder (tconv1 + relu + tconv2 + sigmoid + m2 gating).
// JAX conv_transpose flips the kernel: out[2i+a] = x[i]*W[1-a].
// Weights staged to LDS (per-thread-varying indices). Thread=(parent,a,bb).
// ---------------------------------------------------------------------------
__global__ __launch_bounds__(256)
void k_decoder(const float* __restrict__ h2, const float* __restrict__ m2,
               const float* __restrict__ Wt1, const float* __restrict__ Wt2,
               float* __restrict__ out)
{
    __shared__ float4 w1s[256];   // Wt1: 1024 floats
    __shared__ float4 w2s[32];    // Wt2: 128 floats

    const int tid = threadIdx.x;
    w1s[tid] = ((const float4*)Wt1)[tid];
    if (tid < 32) w2s[tid] = ((const float4*)Wt2)[tid];
    __syncthreads();

    const int T  = blockIdx.x * 256 + tid;          // 0..262143
    const int px = T & 31;
    const int a  = (T >> 5) & 1;
    const int bb = (T >> 6) & 1;
    const int py = (T >> 7) & 31;
    const int pz = (T >> 12) & 31;
    const int b  = T >> 17;
    const int pidx = ((b * 32 + pz) * 32 + py) * 32 + px;

    const float m = m2[pidx];
    const float4 hv = *(const float4*)&h2[pidx * 4];

    const int b0q = ((((1 - a) * 2 + (1 - bb)) * 2) + 1) * 16;  // c=0 -> kc=1
    const int b1q = ((((1 - a) * 2 + (1 - bb)) * 2) + 0) * 16;  // c=1 -> kc=0
    float4 t0q[4], t1q[4];
    #pragma unroll
    for (int q = 0; q < 4; ++q) {
        float4 a0 = w1s[b0q + q],      a1 = w1s[b0q + 4 + q];
        float4 a2 = w1s[b0q + 8 + q],  a3 = w1s[b0q + 12 + q];
        float4 c0 = w1s[b1q + q],      c1 = w1s[b1q + 4 + q];
        float4 c2 = w1s[b1q + 8 + q],  c3 = w1s[b1q + 12 + q];
        float4 s0, s1;
        s0.x = hv.x * a0.x + hv.y * a1.x + hv.z * a2.x + hv.w * a3.x;
        s0.y = hv.x * a0.y + hv.y * a1.y + hv.z * a2.y + hv.w * a3.y;
        s0.z = hv.x * a0.z + hv.y * a1.z + hv.z * a2.z + hv.w * a3.z;
        s0.w = hv.x * a0.w + hv.y * a1.w + hv.z * a2.w + hv.w * a3.w;
        s1.x = hv.x * c0.x + hv.y * c1.x + hv.z * c2.x + hv.w * c3.x;
        s1.y = hv.x * c0.y + hv.y * c1.y + hv.z * c2.y + hv.w * c3.y;
        s1.z = hv.x * c0.z + hv.y * c1.z + hv.z * c2.z + hv.w * c3.z;
        s1.w = hv.x * c0.w + hv.y * c1.w + hv.z * c2.w + hv.w * c3.w;
        t0q[q] = make_float4(fmaxf(s0.x, 0.f), fmaxf(s0.y, 0.f),
                             fmaxf(s0.z, 0.f), fmaxf(s0.w, 0.f));
        t1q[q] = make_float4(fmaxf(s1.x, 0.f), fmaxf(s1.y, 0.f),
                             fmaxf(s1.z, 0.f), fmaxf(s1.w, 0.f));
    }

    #pragma unroll
    for (int e = 0; e < 2; ++e) {
        #pragma unroll
        for (int f = 0; f < 2; ++f) {
            const int d  = 4 * pz + 2 * a + e;
            const int hh = 4 * py + 2 * bb + f;
            const int be = ((1 - e) * 2 + (1 - f)) * 2;
            const float4* wg0 = &w2s[(be + 1) * 4];   // g=0 -> kg=1
            const float4* wg1 = &w2s[(be + 0) * 4];   // g=1 -> kg=0
            float s00 = dot4(t0q[0], wg0[0]) + dot4(t0q[1], wg0[1])
                      + dot4(t0q[2], wg0[2]) + dot4(t0q[3], wg0[3]);
            float s01 = dot4(t0q[0], wg1[0]) + dot4(t0q[1], wg1[1])
                      + dot4(t0q[2], wg1[2]) + dot4(t0q[3], wg1[3]);
            float s10 = dot4(t1q[0], wg0[0]) + dot4(t1q[1], wg0[1])
                      + dot4(t1q[2], wg0[2]) + dot4(t1q[3], wg0[3]);
            float s11 = dot4(t1q[0], wg1[0]) + dot4(t1q[1], wg1[1])
                      + dot4(t1q[2], wg1[2]) + dot4(t1q[3], wg1[3]);
            float4 o;
            o.x = m / (1.f + __expf(-s00));
            o.y = m / (1.f + __expf(-s01));
            o.z = m / (1.f + __expf(-s10));
            o.w = m / (1.f + __expf(-s11));
            *(float4*)&out[((b * G + d) * G + hh) * G + 4 * px] = o;
        }
    }
}

extern "C" void kernel_launch(void* const* d_in, const int* in_sizes, int n_in,
                              void* d_out, int out_size, void* d_ws, size_t ws_size,
                              hipStream_t stream) {
    (void)in_sizes; (void)n_in; (void)out_size; (void)ws_size;
    const float* x   = (const float*)d_in[0];
    const float* W1  = (const float*)d_in[1];
    const float* W2  = (const float*)d_in[2];
    const float* Wt1 = (const float*)d_in[3];
    const float* Wt2 = (const float*)d_in[4];
    const int*   occ = (const int*)d_in[5];
    float* out = (float*)d_out;

    char* ws = (char*)d_ws;
    __half* h1p = (__half*)ws;                                  // 8388608 halfs (16 MB)
    float*  m1  = (float*)(ws + 8388608ull * sizeof(__half));   // 524288 floats
    float*  h2  = m1 + 524288;                                  // 262144 floats
    float*  m2v = h2 + 262144;                                  // 65536 floats

    k_conv1_pool<<<dim3(8, 8, 16), dim3(512), 0, stream>>>(x, occ, W1, h1p, m1);
    k_conv2_pool<<<dim3(8, 8, 16), dim3(256), 0, stream>>>(h1p, m1, W2, h2, m2v);
    k_decoder<<<dim3(1024), dim3(256), 0, stream>>>(h2, m2v, Wt1, Wt2, out);
}

// Round 6
// 200.765 us; speedup vs baseline: 1.5198x; 1.1508x over previous
//
#include <hip/hip_runtime.h>
#include <hip/hip_fp16.h>

#define G 128

union H8 { uint4 u; __half h[8]; __half2 h2[4]; };

// ---------------------------------------------------------------------------
// Kernel A: fused conv1 (3x3x3, 1->16, SAME) + relu + m0-mask + 2x2x2 maxpool.
// DENSE (R1 structure — measured fastest): no lists, no scans, no atomics,
// one barrier. Thread = one pooled voxel, computes its 8 children with
// per-position skip on the center mask; weights uniform -> scalar loads.
// Conv region 8(z)x16(y)x16(x); tile 10x18x18 = 16.2 KB LDS -> ~8 blk/CU.
// Output h1p in fp16 (halves write + conv2 fetch). Grid (8,8,32), block 256.
// ---------------------------------------------------------------------------
__global__ __launch_bounds__(256, 8)
void k_conv1_pool(const float* __restrict__ x, const int* __restrict__ occ,
                  const float* __restrict__ W1,
                  __half* __restrict__ h1p, float* __restrict__ m1)
{
    __shared__ float         sx[10 * 18 * 18];   // [z][y][x]
    __shared__ unsigned char sm[10 * 18 * 18];

    const int bx = blockIdx.x, by = blockIdx.y;
    const int b  = blockIdx.z >> 4, zt = blockIdx.z & 15;
    const int tid = threadIdx.x;

    const int z0 = zt * 8 - 1, y0 = by * 16 - 1, x0 = bx * 16 - 1;
    const int base_b = b * G * G * G;

    #pragma unroll
    for (int r = 0; r < 13; ++r) {
        int i = r * 256 + tid;
        if (i < 3240) {
            int lz = i / 324, rr = i - lz * 324;
            int ly = rr / 18, lx = rr - ly * 18;
            int gz = z0 + lz, gy = y0 + ly, gx = x0 + lx;
            bool inb = (unsigned)gz < 128u && (unsigned)gy < 128u &&
                       (unsigned)gx < 128u;
            int oc = 1; float xv = 0.f;
            if (inb) {                 // two independent loads, both in flight
                int gi = base_b + (gz * G + gy) * G + gx;
                oc = occ[gi];
                xv = x[gi];
            }
            bool mm = inb && (oc == 0);
            sx[i] = mm ? xv : 0.f;
            sm[i] = mm ? 1 : 0;
        }
    }
    __syncthreads();

    // thread -> pooled voxel (tz in [0,4), ty,tx in [0,8))
    const int tx = tid & 7, ty = (tid >> 3) & 7, tz = tid >> 6;

    float best[16];
    #pragma unroll
    for (int c = 0; c < 16; ++c) best[c] = 0.f;
    int anym = 0;

    #pragma unroll
    for (int pos = 0; pos < 8; ++pos) {
        const int dz = pos >> 2, dy = (pos >> 1) & 1, dx = pos & 1;
        const int cz = 2 * tz + dz, cy = 2 * ty + dy, cx = 2 * tx + dx;
        const int cb = (cz + 1) * 324 + (cy + 1) * 18 + (cx + 1);
        if (sm[cb]) {
            anym = 1;
            float acc[16];
            #pragma unroll
            for (int c = 0; c < 16; ++c) acc[c] = 0.f;
            #pragma unroll
            for (int kz = 0; kz < 3; ++kz)
            #pragma unroll
            for (int ky = 0; ky < 3; ++ky)
            #pragma unroll
            for (int kx = 0; kx < 3; ++kx) {
                float v = sx[cb + (kz - 1) * 324 + (ky - 1) * 18 + (kx - 1)];
                const float* w = &W1[((kz * 3 + ky) * 3 + kx) * 16];  // uniform
                #pragma unroll
                for (int c = 0; c < 16; ++c) acc[c] += v * w[c];
            }
            #pragma unroll
            for (int c = 0; c < 16; ++c) {
                float r = acc[c] > 0.f ? acc[c] : 0.f;
                best[c] = best[c] > r ? best[c] : r;
            }
        }
    }

    const int pz = zt * 4 + tz, py = by * 8 + ty, px = bx * 8 + tx;
    const int vidx = ((b * 64 + pz) * 64 + py) * 64 + px;
    H8 p0, p1;
    #pragma unroll
    for (int c = 0; c < 8; ++c) p0.h[c] = __float2half(best[c]);
    #pragma unroll
    for (int c = 0; c < 8; ++c) p1.h[c] = __float2half(best[8 + c]);
    uint4* o = (uint4*)&h1p[(size_t)vidx * 16];
    o[0] = p0.u;
    o[1] = p1.u;
    m1[vidx] = anym ? 1.f : 0.f;
}

// ---------------------------------------------------------------------------
// Kernel B: fused conv2 (3x3x3, 16->4, SAME at 64^3) + relu + m1-mask + pool.
// h1p input fp16. 256 thr, conv region 8^3, thread = 2 x-adjacent conv
// voxels. Channels in two passes of 8 (uint4 tile 17.6 KB -> 8 blk/CU).
// Weights uniform-indexed (scalar loads). Grid (8,8,16).
// ---------------------------------------------------------------------------
__global__ __launch_bounds__(256)
void k_conv2_pool(const __half* __restrict__ h1p, const float* __restrict__ m1,
                  const float* __restrict__ W2,
                  float* __restrict__ h2, float* __restrict__ m2)
{
    __shared__ uint4 tile[10 * 110];   // idx = z*110 + y*11 + x

    const int bx = blockIdx.x, by = blockIdx.y;
    const int b  = blockIdx.z >> 3, bz = blockIdx.z & 7;
    const int tid = threadIdx.x;

    const int dy = tid & 1, dz = (tid >> 1) & 1;
    const int qx = (tid >> 2) & 3, Y = (tid >> 4) & 3, Z = (tid >> 6) & 3;
    const int cx0 = 2 * qx, cy = 2 * Y + dy, cz = 2 * Z + dz;

    const int z0 = bz * 8 - 1, y0 = by * 8 - 1, x0 = bx * 8 - 1;

    float4 acc0 = make_float4(0.f, 0.f, 0.f, 0.f);
    float4 acc1 = make_float4(0.f, 0.f, 0.f, 0.f);

    for (int h = 0; h < 2; ++h) {
        if (h) __syncthreads();
        #pragma unroll
        for (int it = 0; it < 4; ++it) {
            int v = it * 256 + tid;
            if (v < 1000) {
                int z = v / 100, r = v - z * 100, y = r / 10, xx = r - y * 10;
                int gz = z0 + z, gy = y0 + y, gx = x0 + xx;
                uint4 a = make_uint4(0u, 0u, 0u, 0u);
                if ((unsigned)gz < 64u && (unsigned)gy < 64u && (unsigned)gx < 64u)
                    a = ((const uint4*)&h1p[(size_t)(((b * 64 + gz) * 64 + gy) * 64 + gx) * 16])[h];
                tile[z * 110 + y * 11 + xx] = a;
            }
        }
        __syncthreads();

        #pragma unroll
        for (int kz = 0; kz < 3; ++kz)
        #pragma unroll
        for (int ky = 0; ky < 3; ++ky) {
            const int rb = (cz + kz) * 110 + (cy + ky) * 11 + cx0;
            float f[4][8];
            #pragma unroll
            for (int xi = 0; xi < 4; ++xi) {
                H8 hh; hh.u = tile[rb + xi];
                #pragma unroll
                for (int q = 0; q < 4; ++q) {
                    float2 f2 = __half22float2(hh.h2[q]);
                    f[xi][2 * q]     = f2.x;
                    f[xi][2 * q + 1] = f2.y;
                }
            }
            const float* wt = &W2[((kz * 3 + ky) * 3) * 64 + h * 32];
            #pragma unroll
            for (int kx = 0; kx < 3; ++kx) {
                const float* w = wt + kx * 64;   // uniform -> scalar loads
                #pragma unroll
                for (int j = 0; j < 2; ++j) {
                    const float* ff = f[kx + j];
                    float4* acc = j ? &acc1 : &acc0;
                    #pragma unroll
                    for (int ci = 0; ci < 8; ++ci) {
                        float vv = ff[ci];
                        acc->x += vv * w[ci * 4 + 0];
                        acc->y += vv * w[ci * 4 + 1];
                        acc->z += vv * w[ci * 4 + 2];
                        acc->w += vv * w[ci * 4 + 3];
                    }
                }
            }
        }
    }

    const int gcz = bz * 8 + cz, gcy = by * 8 + cy, gcx = bx * 8 + cx0;
    const float mv0 = m1[((b * 64 + gcz) * 64 + gcy) * 64 + gcx];
    const float mv1 = m1[((b * 64 + gcz) * 64 + gcy) * 64 + gcx + 1];
    float m = fmaxf(mv0, mv1);
    float r0 = fmaxf(fmaxf(acc0.x, 0.f) * mv0, fmaxf(acc1.x, 0.f) * mv1);
    float r1 = fmaxf(fmaxf(acc0.y, 0.f) * mv0, fmaxf(acc1.y, 0.f) * mv1);
    float r2 = fmaxf(fmaxf(acc0.z, 0.f) * mv0, fmaxf(acc1.z, 0.f) * mv1);
    float r3 = fmaxf(fmaxf(acc0.w, 0.f) * mv0, fmaxf(acc1.w, 0.f) * mv1);

    #pragma unroll
    for (int mask = 1; mask <= 2; mask <<= 1) {
        r0 = fmaxf(r0, __shfl_xor(r0, mask));
        r1 = fmaxf(r1, __shfl_xor(r1, mask));
        r2 = fmaxf(r2, __shfl_xor(r2, mask));
        r3 = fmaxf(r3, __shfl_xor(r3, mask));
        m  = fmaxf(m,  __shfl_xor(m,  mask));
    }
    if ((tid & 3) == 0) {
        int pz = bz * 4 + Z, py = by * 4 + Y, px = bx * 4 + qx;
        int oidx = ((b * 32 + pz) * 32 + py) * 32 + px;
        *(float4*)&h2[oidx * 4] = make_float4(r0, r1, r2, r3);
        m2[oidx] = m;
    }
}

__device__ __forceinline__ float dot4(float4 a, float4 b) {
    return a.x * b.x + a.y * b.y + a.z * b.z + a.w * b.w;
}

// ---------------------------------------------------------------------------
// Kernel C: fused decoder (tconv1 + relu + tconv2 + sigmoid + m2 gating).
// JAX conv_transpose flips the kernel: out[2i+a] = x[i]*W[1-a].
// Weights staged to LDS. Thread = (parent, a, bb); 4 float4 stores each.
// ---------------------------------------------------------------------------
__global__ __launch_bounds__(256)
void k_decoder(const float* __restrict__ h2, const float* __restrict__ m2,
               const float* __restrict__ Wt1, const float* __restrict__ Wt2,
               float* __restrict__ out)
{
    __shared__ float4 w1s[256];   // Wt1: 1024 floats
    __shared__ float4 w2s[32];    // Wt2: 128 floats

    const int tid = threadIdx.x;
    w1s[tid] = ((const float4*)Wt1)[tid];
    if (tid < 32) w2s[tid] = ((const float4*)Wt2)[tid];
    __syncthreads();

    const int T  = blockIdx.x * 256 + tid;          // 0..262143
    const int px = T & 31;
    const int a  = (T >> 5) & 1;
    const int bb = (T >> 6) & 1;
    const int py = (T >> 7) & 31;
    const int pz = (T >> 12) & 31;
    const int b  = T >> 17;
    const int pidx = ((b * 32 + pz) * 32 + py) * 32 + px;

    const float m = m2[pidx];
    const float4 hv = *(const float4*)&h2[pidx * 4];

    const int b0q = ((((1 - a) * 2 + (1 - bb)) * 2) + 1) * 16;  // c=0 -> kc=1
    const int b1q = ((((1 - a) * 2 + (1 - bb)) * 2) + 0) * 16;  // c=1 -> kc=0
    float4 t0q[4], t1q[4];
    #pragma unroll
    for (int q = 0; q < 4; ++q) {
        float4 a0 = w1s[b0q + q],      a1 = w1s[b0q + 4 + q];
        float4 a2 = w1s[b0q + 8 + q],  a3 = w1s[b0q + 12 + q];
        float4 c0 = w1s[b1q + q],      c1 = w1s[b1q + 4 + q];
        float4 c2 = w1s[b1q + 8 + q],  c3 = w1s[b1q + 12 + q];
        float4 s0, s1;
        s0.x = hv.x * a0.x + hv.y * a1.x + hv.z * a2.x + hv.w * a3.x;
        s0.y = hv.x * a0.y + hv.y * a1.y + hv.z * a2.y + hv.w * a3.y;
        s0.z = hv.x * a0.z + hv.y * a1.z + hv.z * a2.z + hv.w * a3.z;
        s0.w = hv.x * a0.w + hv.y * a1.w + hv.z * a2.w + hv.w * a3.w;
        s1.x = hv.x * c0.x + hv.y * c1.x + hv.z * c2.x + hv.w * c3.x;
        s1.y = hv.x * c0.y + hv.y * c1.y + hv.z * c2.y + hv.w * c3.y;
        s1.z = hv.x * c0.z + hv.y * c1.z + hv.z * c2.z + hv.w * c3.z;
        s1.w = hv.x * c0.w + hv.y * c1.w + hv.z * c2.w + hv.w * c3.w;
        t0q[q] = make_float4(fmaxf(s0.x, 0.f), fmaxf(s0.y, 0.f),
                             fmaxf(s0.z, 0.f), fmaxf(s0.w, 0.f));
        t1q[q] = make_float4(fmaxf(s1.x, 0.f), fmaxf(s1.y, 0.f),
                             fmaxf(s1.z, 0.f), fmaxf(s1.w, 0.f));
    }

    #pragma unroll
    for (int e = 0; e < 2; ++e) {
        #pragma unroll
        for (int f = 0; f < 2; ++f) {
            const int d  = 4 * pz + 2 * a + e;
            const int hh = 4 * py + 2 * bb + f;
            const int be = ((1 - e) * 2 + (1 - f)) * 2;
            const float4* wg0 = &w2s[(be + 1) * 4];   // g=0 -> kg=1
            const float4* wg1 = &w2s[(be + 0) * 4];   // g=1 -> kg=0
            float s00 = dot4(t0q[0], wg0[0]) + dot4(t0q[1], wg0[1])
                      + dot4(t0q[2], wg0[2]) + dot4(t0q[3], wg0[3]);
            float s01 = dot4(t0q[0], wg1[0]) + dot4(t0q[1], wg1[1])
                      + dot4(t0q[2], wg1[2]) + dot4(t0q[3], wg1[3]);
            float s10 = dot4(t1q[0], wg0[0]) + dot4(t1q[1], wg0[1])
                      + dot4(t1q[2], wg0[2]) + dot4(t1q[3], wg0[3]);
            float s11 = dot4(t1q[0], wg1[0]) + dot4(t1q[1], wg1[1])
                      + dot4(t1q[2], wg1[2]) + dot4(t1q[3], wg1[3]);
            float4 o;
            o.x = m / (1.f + __expf(-s00));
            o.y = m / (1.f + __expf(-s01));
            o.z = m / (1.f + __expf(-s10));
            o.w = m / (1.f + __expf(-s11));
            *(float4*)&out[((b * G + d) * G + hh) * G + 4 * px] = o;
        }
    }
}

extern "C" void kernel_launch(void* const* d_in, const int* in_sizes, int n_in,
                              void* d_out, int out_size, void* d_ws, size_t ws_size,
                              hipStream_t stream) {
    (void)in_sizes; (void)n_in; (void)out_size; (void)ws_size;
    const float* x   = (const float*)d_in[0];
    const float* W1  = (const float*)d_in[1];
    const float* W2  = (const float*)d_in[2];
    const float* Wt1 = (const float*)d_in[3];
    const float* Wt2 = (const float*)d_in[4];
    const int*   occ = (const int*)d_in[5];
    float* out = (float*)d_out;

    char* ws = (char*)d_ws;
    __half* h1p = (__half*)ws;                                  // 8388608 halfs (16 MB)
    float*  m1  = (float*)(ws + 8388608ull * sizeof(__half));   // 524288 floats
    float*  h2  = m1 + 524288;                                  // 262144 floats
    float*  m2v = h2 + 262144;                                  // 65536 floats

    k_conv1_pool<<<dim3(8, 8, 32), dim3(256), 0, stream>>>(x, occ, W1, h1p, m1);
    k_conv2_pool<<<dim3(8, 8, 16), dim3(256), 0, stream>>>(h1p, m1, W2, h2, m2v);
    k_decoder<<<dim3(1024), dim3(256), 0, stream>>>(h2, m2v, Wt1, Wt2, out);
}

// Round 7
// 187.493 us; speedup vs baseline: 1.6273x; 1.0708x over previous
//
#include <hip/hip_runtime.h>
#include <hip/hip_fp16.h>

#define G 128

typedef _Float16 h2_t __attribute__((ext_vector_type(2)));

union H8  { uint4 u; __half h[8]; };
union U16 { uint4 u; h2_t h2[4]; };

__device__ __forceinline__ float dot2f(h2_t a, h2_t b, float c) {
#if __has_builtin(__builtin_amdgcn_fdot2)
    return __builtin_amdgcn_fdot2(a, b, c, false);
#else
    return c + (float)a.x * (float)b.x + (float)a.y * (float)b.y;
#endif
}

// ---------------------------------------------------------------------------
// Kernel P: convert W2 (fp32, [t=27][ci=16][co=4]) to fp16 half2 layout
// w2h[t*32 + co*8 + p] = (W2[t][2p][co], W2[t][2p+1][co]).  864 half2.
// ---------------------------------------------------------------------------
__global__ void k_prep(const float* __restrict__ W2, __half* __restrict__ w2h)
{
    int i = blockIdx.x * 256 + threadIdx.x;
    if (i < 864) {
        int t = i >> 5, r = i & 31, co = r >> 3, p = r & 7;
        w2h[2 * i]     = __float2half(W2[t * 64 + (2 * p) * 4 + co]);
        w2h[2 * i + 1] = __float2half(W2[t * 64 + (2 * p + 1) * 4 + co]);
    }
}

// ---------------------------------------------------------------------------
// Kernel A: fused conv1 (3x3x3, 1->16, SAME) + relu + m0-mask + 2x2x2 maxpool.
// DENSE R6 structure. ONLY change vs R6: __launch_bounds__(256,4) —
// R6's (256,8) forced VGPR=32 -> scratch spills (WRITE 31.6MB vs 18.8
// structural). Cap 128 VGPR so acc[16]+best[16] live in registers.
// ---------------------------------------------------------------------------
__global__ __launch_bounds__(256, 4)
void k_conv1_pool(const float* __restrict__ x, const int* __restrict__ occ,
                  const float* __restrict__ W1,
                  __half* __restrict__ h1p, float* __restrict__ m1)
{
    __shared__ float         sx[10 * 18 * 18];   // [z][y][x]
    __shared__ unsigned char sm[10 * 18 * 18];

    const int bx = blockIdx.x, by = blockIdx.y;
    const int b  = blockIdx.z >> 4, zt = blockIdx.z & 15;
    const int tid = threadIdx.x;

    const int z0 = zt * 8 - 1, y0 = by * 16 - 1, x0 = bx * 16 - 1;
    const int base_b = b * G * G * G;

    #pragma unroll
    for (int r = 0; r < 13; ++r) {
        int i = r * 256 + tid;
        if (i < 3240) {
            int lz = i / 324, rr = i - lz * 324;
            int ly = rr / 18, lx = rr - ly * 18;
            int gz = z0 + lz, gy = y0 + ly, gx = x0 + lx;
            bool inb = (unsigned)gz < 128u && (unsigned)gy < 128u &&
                       (unsigned)gx < 128u;
            int oc = 1; float xv = 0.f;
            if (inb) {
                int gi = base_b + (gz * G + gy) * G + gx;
                oc = occ[gi];
                xv = x[gi];
            }
            bool mm = inb && (oc == 0);
            sx[i] = mm ? xv : 0.f;
            sm[i] = mm ? 1 : 0;
        }
    }
    __syncthreads();

    const int tx = tid & 7, ty = (tid >> 3) & 7, tz = tid >> 6;

    float best[16];
    #pragma unroll
    for (int c = 0; c < 16; ++c) best[c] = 0.f;
    int anym = 0;

    #pragma unroll
    for (int pos = 0; pos < 8; ++pos) {
        const int dz = pos >> 2, dy = (pos >> 1) & 1, dx = pos & 1;
        const int cz = 2 * tz + dz, cy = 2 * ty + dy, cx = 2 * tx + dx;
        const int cb = (cz + 1) * 324 + (cy + 1) * 18 + (cx + 1);
        if (sm[cb]) {
            anym = 1;
            float acc[16];
            #pragma unroll
            for (int c = 0; c < 16; ++c) acc[c] = 0.f;
            #pragma unroll
            for (int kz = 0; kz < 3; ++kz)
            #pragma unroll
            for (int ky = 0; ky < 3; ++ky)
            #pragma unroll
            for (int kx = 0; kx < 3; ++kx) {
                float v = sx[cb + (kz - 1) * 324 + (ky - 1) * 18 + (kx - 1)];
                const float* w = &W1[((kz * 3 + ky) * 3 + kx) * 16];  // uniform
                #pragma unroll
                for (int c = 0; c < 16; ++c) acc[c] += v * w[c];
            }
            #pragma unroll
            for (int c = 0; c < 16; ++c) {
                float r = acc[c] > 0.f ? acc[c] : 0.f;
                best[c] = best[c] > r ? best[c] : r;
            }
        }
    }

    const int pz = zt * 4 + tz, py = by * 8 + ty, px = bx * 8 + tx;
    const int vidx = ((b * 64 + pz) * 64 + py) * 64 + px;
    H8 p0, p1;
    #pragma unroll
    for (int c = 0; c < 8; ++c) p0.h[c] = __float2half(best[c]);
    #pragma unroll
    for (int c = 0; c < 8; ++c) p1.h[c] = __float2half(best[8 + c]);
    uint4* o = (uint4*)&h1p[(size_t)vidx * 16];
    o[0] = p0.u;
    o[1] = p1.u;
    m1[vidx] = anym ? 1.f : 0.f;
}

// ---------------------------------------------------------------------------
// Kernel B: fused conv2 (3x3x3, 16->4, SAME at 64^3) + relu + m1-mask + pool.
// fp16 dot2 path: taps stay fp16 (v_dot2_f32_f16 = 2 MAC/instr, fp32 acc),
// weights pre-converted by k_prep, uniform-indexed -> scalar loads.
// SINGLE-pass 16-ch tile (35.2 KB; halves the global fetch vs 2-pass).
// 256 thr, conv region 8^3, thread = 2 x-adjacent conv voxels. Grid (8,8,16).
// ---------------------------------------------------------------------------
__global__ __launch_bounds__(256, 4)
void k_conv2_pool(const __half* __restrict__ h1p, const float* __restrict__ m1,
                  const h2_t* __restrict__ w2h,
                  float* __restrict__ h2, float* __restrict__ m2)
{
    __shared__ uint4 tile[1100 * 2];   // 10*10*11 voxels * 32B = 35.2 KB

    const int bx = blockIdx.x, by = blockIdx.y;
    const int b  = blockIdx.z >> 3, bz = blockIdx.z & 7;
    const int tid = threadIdx.x;

    const int z0 = bz * 8 - 1, y0 = by * 8 - 1, x0 = bx * 8 - 1;

    #pragma unroll
    for (int it = 0; it < 8; ++it) {
        int g = it * 256 + tid;          // 2000 uint4 to stage
        if (g < 2000) {
            int vox = g >> 1, h = g & 1;
            int z = vox / 100, r = vox - z * 100, y = r / 10, xx = r - y * 10;
            int gz = z0 + z, gy = y0 + y, gx = x0 + xx;
            uint4 a = make_uint4(0u, 0u, 0u, 0u);
            if ((unsigned)gz < 64u && (unsigned)gy < 64u && (unsigned)gx < 64u)
                a = ((const uint4*)&h1p[(size_t)(((b * 64 + gz) * 64 + gy) * 64 + gx) * 16])[h];
            tile[(z * 110 + y * 11 + xx) * 2 + h] = a;
        }
    }
    __syncthreads();

    const int dy = tid & 1, dz = (tid >> 1) & 1;
    const int qx = (tid >> 2) & 3, Y = (tid >> 4) & 3, Z = (tid >> 6) & 3;
    const int cx0 = 2 * qx, cy = 2 * Y + dy, cz = 2 * Z + dz;

    float acc[2][4] = {{0.f, 0.f, 0.f, 0.f}, {0.f, 0.f, 0.f, 0.f}};

    #pragma unroll
    for (int kz = 0; kz < 3; ++kz)
    #pragma unroll
    for (int ky = 0; ky < 3; ++ky) {
        const int rb = ((cz + kz) * 110 + (cy + ky) * 11 + cx0) * 2;
        h2_t hp[4][8];
        #pragma unroll
        for (int xi = 0; xi < 4; ++xi) {
            U16 a, c;
            a.u = tile[rb + xi * 2];
            c.u = tile[rb + xi * 2 + 1];
            #pragma unroll
            for (int p = 0; p < 4; ++p) { hp[xi][p] = a.h2[p]; hp[xi][4 + p] = c.h2[p]; }
        }
        const int t3 = (kz * 3 + ky) * 3;
        #pragma unroll
        for (int kx = 0; kx < 3; ++kx) {
            const h2_t* w = w2h + (t3 + kx) * 32;   // uniform -> s_load
            #pragma unroll
            for (int j = 0; j < 2; ++j) {
                #pragma unroll
                for (int co = 0; co < 4; ++co) {
                    float a = acc[j][co];
                    #pragma unroll
                    for (int p = 0; p < 8; ++p)
                        a = dot2f(hp[kx + j][p], w[co * 8 + p], a);
                    acc[j][co] = a;
                }
            }
        }
    }

    const int gcz = bz * 8 + cz, gcy = by * 8 + cy, gcx = bx * 8 + cx0;
    const float mv0 = m1[((b * 64 + gcz) * 64 + gcy) * 64 + gcx];
    const float mv1 = m1[((b * 64 + gcz) * 64 + gcy) * 64 + gcx + 1];
    float m = fmaxf(mv0, mv1);
    float r0 = fmaxf(fmaxf(acc[0][0], 0.f) * mv0, fmaxf(acc[1][0], 0.f) * mv1);
    float r1 = fmaxf(fmaxf(acc[0][1], 0.f) * mv0, fmaxf(acc[1][1], 0.f) * mv1);
    float r2 = fmaxf(fmaxf(acc[0][2], 0.f) * mv0, fmaxf(acc[1][2], 0.f) * mv1);
    float r3 = fmaxf(fmaxf(acc[0][3], 0.f) * mv0, fmaxf(acc[1][3], 0.f) * mv1);

    #pragma unroll
    for (int mask = 1; mask <= 2; mask <<= 1) {
        r0 = fmaxf(r0, __shfl_xor(r0, mask));
        r1 = fmaxf(r1, __shfl_xor(r1, mask));
        r2 = fmaxf(r2, __shfl_xor(r2, mask));
        r3 = fmaxf(r3, __shfl_xor(r3, mask));
        m  = fmaxf(m,  __shfl_xor(m,  mask));
    }
    if ((tid & 3) == 0) {
        int pz = bz * 4 + Z, py = by * 4 + Y, px = bx * 4 + qx;
        int oidx = ((b * 32 + pz) * 32 + py) * 32 + px;
        *(float4*)&h2[oidx * 4] = make_float4(r0, r1, r2, r3);
        m2[oidx] = m;
    }
}

__device__ __forceinline__ float dot4(float4 a, float4 b) {
    return a.x * b.x + a.y * b.y + a.z * b.z + a.w * b.w;
}

// ---------------------------------------------------------------------------
// Kernel C: fused decoder (tconv1 + relu + tconv2 + sigmoid + m2 gating).
// JAX conv_transpose flips the kernel: out[2i+a] = x[i]*W[1-a].
// Weights staged to LDS. Thread = (parent, a, bb); 4 float4 stores each.
// ---------------------------------------------------------------------------
__global__ __launch_bounds__(256)
void k_decoder(const float* __restrict__ h2, const float* __restrict__ m2,
               const float* __restrict__ Wt1, const float* __restrict__ Wt2,
               float* __restrict__ out)
{
    __shared__ float4 w1s[256];   // Wt1: 1024 floats
    __shared__ float4 w2s[32];    // Wt2: 128 floats

    const int tid = threadIdx.x;
    w1s[tid] = ((const float4*)Wt1)[tid];
    if (tid < 32) w2s[tid] = ((const float4*)Wt2)[tid];
    __syncthreads();

    const int T  = blockIdx.x * 256 + tid;          // 0..262143
    const int px = T & 31;
    const int a  = (T >> 5) & 1;
    const int bb = (T >> 6) & 1;
    const int py = (T >> 7) & 31;
    const int pz = (T >> 12) & 31;
    const int b  = T >> 17;
    const int pidx = ((b * 32 + pz) * 32 + py) * 32 + px;

    const float m = m2[pidx];
    const float4 hv = *(const float4*)&h2[pidx * 4];

    const int b0q = ((((1 - a) * 2 + (1 - bb)) * 2) + 1) * 16;  // c=0 -> kc=1
    const int b1q = ((((1 - a) * 2 + (1 - bb)) * 2) + 0) * 16;  // c=1 -> kc=0
    float4 t0q[4], t1q[4];
    #pragma unroll
    for (int q = 0; q < 4; ++q) {
        float4 a0 = w1s[b0q + q],      a1 = w1s[b0q + 4 + q];
        float4 a2 = w1s[b0q + 8 + q],  a3 = w1s[b0q + 12 + q];
        float4 c0 = w1s[b1q + q],      c1 = w1s[b1q + 4 + q];
        float4 c2 = w1s[b1q + 8 + q],  c3 = w1s[b1q + 12 + q];
        float4 s0, s1;
        s0.x = hv.x * a0.x + hv.y * a1.x + hv.z * a2.x + hv.w * a3.x;
        s0.y = hv.x * a0.y + hv.y * a1.y + hv.z * a2.y + hv.w * a3.y;
        s0.z = hv.x * a0.z + hv.y * a1.z + hv.z * a2.z + hv.w * a3.z;
        s0.w = hv.x * a0.w + hv.y * a1.w + hv.z * a2.w + hv.w * a3.w;
        s1.x = hv.x * c0.x + hv.y * c1.x + hv.z * c2.x + hv.w * c3.x;
        s1.y = hv.x * c0.y + hv.y * c1.y + hv.z * c2.y + hv.w * c3.y;
        s1.z = hv.x * c0.z + hv.y * c1.z + hv.z * c2.z + hv.w * c3.z;
        s1.w = hv.x * c0.w + hv.y * c1.w + hv.z * c2.w + hv.w * c3.w;
        t0q[q] = make_float4(fmaxf(s0.x, 0.f), fmaxf(s0.y, 0.f),
                             fmaxf(s0.z, 0.f), fmaxf(s0.w, 0.f));
        t1q[q] = make_float4(fmaxf(s1.x, 0.f), fmaxf(s1.y, 0.f),
                             fmaxf(s1.z, 0.f), fmaxf(s1.w, 0.f));
    }

    #pragma unroll
    for (int e = 0; e < 2; ++e) {
        #pragma unroll
        for (int f = 0; f < 2; ++f) {
            const int d  = 4 * pz + 2 * a + e;
            const int hh = 4 * py + 2 * bb + f;
            const int be = ((1 - e) * 2 + (1 - f)) * 2;
            const float4* wg0 = &w2s[(be + 1) * 4];   // g=0 -> kg=1
            const float4* wg1 = &w2s[(be + 0) * 4];   // g=1 -> kg=0
            float s00 = dot4(t0q[0], wg0[0]) + dot4(t0q[1], wg0[1])
                      + dot4(t0q[2], wg0[2]) + dot4(t0q[3], wg0[3]);
            float s01 = dot4(t0q[0], wg1[0]) + dot4(t0q[1], wg1[1])
                      + dot4(t0q[2], wg1[2]) + dot4(t0q[3], wg1[3]);
            float s10 = dot4(t1q[0], wg0[0]) + dot4(t1q[1], wg0[1])
                      + dot4(t1q[2], wg0[2]) + dot4(t1q[3], wg0[3]);
            float s11 = dot4(t1q[0], wg1[0]) + dot4(t1q[1], wg1[1])
                      + dot4(t1q[2], wg1[2]) + dot4(t1q[3], wg1[3]);
            float4 o;
            o.x = m / (1.f + __expf(-s00));
            o.y = m / (1.f + __expf(-s01));
            o.z = m / (1.f + __expf(-s10));
            o.w = m / (1.f + __expf(-s11));
            *(float4*)&out[((b * G + d) * G + hh) * G + 4 * px] = o;
        }
    }
}

extern "C" void kernel_launch(void* const* d_in, const int* in_sizes, int n_in,
                              void* d_out, int out_size, void* d_ws, size_t ws_size,
                              hipStream_t stream) {
    (void)in_sizes; (void)n_in; (void)out_size; (void)ws_size;
    const float* x   = (const float*)d_in[0];
    const float* W1  = (const float*)d_in[1];
    const float* W2  = (const float*)d_in[2];
    const float* Wt1 = (const float*)d_in[3];
    const float* Wt2 = (const float*)d_in[4];
    const int*   occ = (const int*)d_in[5];
    float* out = (float*)d_out;

    char* ws = (char*)d_ws;
    __half* h1p = (__half*)ws;                                  // 16 MB
    float*  m1  = (float*)(ws + 8388608ull * sizeof(__half));   // 2 MB
    float*  h2  = m1 + 524288;                                  // 1 MB
    float*  m2v = h2 + 262144;                                  // 256 KB
    __half* w2h = (__half*)(m2v + 65536);                       // 3456 B

    k_prep<<<dim3(4), dim3(256), 0, stream>>>(W2, w2h);
    k_conv1_pool<<<dim3(8, 8, 32), dim3(256), 0, stream>>>(x, occ, W1, h1p, m1);
    k_conv2_pool<<<dim3(8, 8, 16), dim3(256), 0, stream>>>(h1p, m1, (const h2_t*)w2h, h2, m2v);
    k_decoder<<<dim3(1024), dim3(256), 0, stream>>>(h2, m2v, Wt1, Wt2, out);
}

// Round 8
// 168.458 us; speedup vs baseline: 1.8112x; 1.1130x over previous
//
#include <hip/hip_runtime.h>
#include <hip/hip_fp16.h>

#define G 128

typedef _Float16 h2_t __attribute__((ext_vector_type(2)));

union U16 { uint4 u; h2_t h2[4]; };
union HV  { uint4 u; h2_t h2[4]; };

__device__ __forceinline__ float dot2f(h2_t a, h2_t b, float c) {
#if __has_builtin(__builtin_amdgcn_fdot2)
    return __builtin_amdgcn_fdot2(a, b, c, false);
#else
    return c + (float)a.x * (float)b.x + (float)a.y * (float)b.y;
#endif
}

__device__ __forceinline__ h2_t h2max(h2_t a, h2_t b) {
#if __has_builtin(__builtin_elementwise_max)
    return __builtin_elementwise_max(a, b);
#else
    h2_t r;
    r.x = a.x > b.x ? a.x : b.x;
    r.y = a.y > b.y ? a.y : b.y;
    return r;
#endif
}

// ---------------------------------------------------------------------------
// Kernel P: pack weights to fp16 half2.
//  w1h[tap*8 + p]       = (W1[tap][2p],   W1[tap][2p+1])          216 h2
//  w2h[t*32 + co*8 + p] = (W2[t][2p][co], W2[t][2p+1][co])        864 h2
// ---------------------------------------------------------------------------
__global__ void k_prep(const float* __restrict__ W1, const float* __restrict__ W2,
                       __half* __restrict__ w1h, __half* __restrict__ w2h)
{
    int i = blockIdx.x * 256 + threadIdx.x;
    if (i < 216) {
        int tap = i >> 3, p = i & 7;
        w1h[2 * i]     = __float2half(W1[tap * 16 + 2 * p]);
        w1h[2 * i + 1] = __float2half(W1[tap * 16 + 2 * p + 1]);
    }
    if (i < 864) {
        int t = i >> 5, r = i & 31, co = r >> 3, p = r & 7;
        w2h[2 * i]     = __float2half(W2[t * 64 + (2 * p) * 4 + co]);
        w2h[2 * i + 1] = __float2half(W2[t * 64 + (2 * p + 1) * 4 + co]);
    }
}

// ---------------------------------------------------------------------------
// Kernel A: fused conv1 (3x3x3, 1->16, SAME) + relu + m0-mask + 2x2x2 maxpool.
// Packed-fp16 dense: sx tile fp16; inner loop = ds_read_u16 + pack + 8
// v_pk_fma_f16 per tap (2 MAC/instr, vs 16 v_fmac_f32); relu+pool via
// v_pk_max_f16; stores the 8 h2 accumulators directly (h1p is fp16).
// Conv region 8(z)x16x16, block 256, grid (8,8,32). LDS ~10KB.
// ---------------------------------------------------------------------------
__global__ __launch_bounds__(256, 4)
void k_conv1_pool(const float* __restrict__ x, const int* __restrict__ occ,
                  const h2_t* __restrict__ w1h,
                  __half* __restrict__ h1p, float* __restrict__ m1)
{
    __shared__ _Float16      sx[10 * 18 * 18];   // [z][y][x]
    __shared__ unsigned char sm[10 * 18 * 18];

    const int bx = blockIdx.x, by = blockIdx.y;
    const int b  = blockIdx.z >> 4, zt = blockIdx.z & 15;
    const int tid = threadIdx.x;

    const int z0 = zt * 8 - 1, y0 = by * 16 - 1, x0 = bx * 16 - 1;
    const int base_b = b * G * G * G;

    #pragma unroll
    for (int r = 0; r < 13; ++r) {
        int i = r * 256 + tid;
        if (i < 3240) {
            int lz = i / 324, rr = i - lz * 324;
            int ly = rr / 18, lx = rr - ly * 18;
            int gz = z0 + lz, gy = y0 + ly, gx = x0 + lx;
            bool inb = (unsigned)gz < 128u && (unsigned)gy < 128u &&
                       (unsigned)gx < 128u;
            int oc = 1; float xv = 0.f;
            if (inb) {                 // two independent loads, both in flight
                int gi = base_b + (gz * G + gy) * G + gx;
                oc = occ[gi];
                xv = x[gi];
            }
            bool mm = inb && (oc == 0);
            sx[i] = mm ? (_Float16)xv : (_Float16)0.f;
            sm[i] = mm ? 1 : 0;
        }
    }
    __syncthreads();

    const int tx = tid & 7, ty = (tid >> 3) & 7, tz = tid >> 6;

    const h2_t zero = (h2_t)(_Float16)0.f;
    h2_t best[8];
    #pragma unroll
    for (int c = 0; c < 8; ++c) best[c] = zero;
    int anym = 0;

    #pragma unroll
    for (int pos = 0; pos < 8; ++pos) {
        const int dz = pos >> 2, dy = (pos >> 1) & 1, dx = pos & 1;
        const int cz = 2 * tz + dz, cy = 2 * ty + dy, cx = 2 * tx + dx;
        const int cb = (cz + 1) * 324 + (cy + 1) * 18 + (cx + 1);
        if (sm[cb]) {
            anym = 1;
            h2_t acc[8];
            #pragma unroll
            for (int c = 0; c < 8; ++c) acc[c] = zero;
            #pragma unroll
            for (int kz = 0; kz < 3; ++kz)
            #pragma unroll
            for (int ky = 0; ky < 3; ++ky)
            #pragma unroll
            for (int kx = 0; kx < 3; ++kx) {
                _Float16 v = sx[cb + (kz - 1) * 324 + (ky - 1) * 18 + (kx - 1)];
                h2_t v2 = {v, v};
                const h2_t* w = &w1h[((kz * 3 + ky) * 3 + kx) * 8];   // uniform
                #pragma unroll
                for (int c = 0; c < 8; ++c) acc[c] = v2 * w[c] + acc[c];
            }
            #pragma unroll
            for (int c = 0; c < 8; ++c) best[c] = h2max(best[c], h2max(acc[c], zero));
        }
    }

    const int pz = zt * 4 + tz, py = by * 8 + ty, px = bx * 8 + tx;
    const int vidx = ((b * 64 + pz) * 64 + py) * 64 + px;
    HV p0, p1;
    #pragma unroll
    for (int c = 0; c < 4; ++c) { p0.h2[c] = best[c]; p1.h2[c] = best[4 + c]; }
    uint4* o = (uint4*)&h1p[(size_t)vidx * 16];
    o[0] = p0.u;
    o[1] = p1.u;
    m1[vidx] = anym ? 1.f : 0.f;
}

// ---------------------------------------------------------------------------
// Kernel B: fused conv2 (3x3x3, 16->4, SAME at 64^3) + relu + m1-mask + pool.
// Occupancy fix vs R7: 128-thr blocks, conv region 8x8x4, grid (8,8,32) =
// 4096 blocks -> 16 blk/CU (32 waves; R7 was grid-capped at 4 blk/CU).
// 2-pass 8-channel tile (6x10x11 uint4 = 10.6 KB). dot2 fp16 math,
// weights pre-packed, uniform-indexed -> scalar loads.
// ---------------------------------------------------------------------------
__global__ __launch_bounds__(128)
void k_conv2_pool(const __half* __restrict__ h1p, const float* __restrict__ m1,
                  const h2_t* __restrict__ w2h,
                  float* __restrict__ h2, float* __restrict__ m2)
{
    __shared__ uint4 tile[660];   // idx = z*110 + y*11 + x, z in [0,6)

    const int bx = blockIdx.x, by = blockIdx.y;
    const int b  = blockIdx.z >> 4, z4 = blockIdx.z & 15;
    const int tid = threadIdx.x;

    const int z0 = z4 * 4 - 1, y0 = by * 8 - 1, x0 = bx * 8 - 1;

    const int dy = tid & 1, dz = (tid >> 1) & 1;
    const int qx = (tid >> 2) & 3, Y = (tid >> 4) & 3, Z = (tid >> 6) & 1;
    const int cx0 = 2 * qx, cy = 2 * Y + dy, cz = 2 * Z + dz;

    float acc[2][4] = {{0.f, 0.f, 0.f, 0.f}, {0.f, 0.f, 0.f, 0.f}};

    for (int h = 0; h < 2; ++h) {
        if (h) __syncthreads();
        #pragma unroll
        for (int it = 0; it < 6; ++it) {
            int g = it * 128 + tid;
            if (g < 660) {
                int z = g / 110, r = g - z * 110, y = r / 11, xx = r - y * 11;
                int gz = z0 + z, gy = y0 + y, gx = x0 + xx;
                uint4 a = make_uint4(0u, 0u, 0u, 0u);
                if ((unsigned)gz < 64u && (unsigned)gy < 64u && (unsigned)gx < 64u)
                    a = ((const uint4*)&h1p[(size_t)(((b * 64 + gz) * 64 + gy) * 64 + gx) * 16])[h];
                tile[g] = a;
            }
        }
        __syncthreads();

        #pragma unroll
        for (int kz = 0; kz < 3; ++kz)
        #pragma unroll
        for (int ky = 0; ky < 3; ++ky) {
            const int rb = (cz + kz) * 110 + (cy + ky) * 11 + cx0;
            h2_t hp[4][4];
            #pragma unroll
            for (int xi = 0; xi < 4; ++xi) {
                U16 a; a.u = tile[rb + xi];
                #pragma unroll
                for (int p = 0; p < 4; ++p) hp[xi][p] = a.h2[p];
            }
            const int t3 = (kz * 3 + ky) * 3;
            #pragma unroll
            for (int kx = 0; kx < 3; ++kx) {
                const h2_t* w = w2h + (t3 + kx) * 32 + 4 * h;   // uniform
                #pragma unroll
                for (int j = 0; j < 2; ++j) {
                    #pragma unroll
                    for (int co = 0; co < 4; ++co) {
                        float a = acc[j][co];
                        #pragma unroll
                        for (int p = 0; p < 4; ++p)
                            a = dot2f(hp[kx + j][p], w[co * 8 + p], a);
                        acc[j][co] = a;
                    }
                }
            }
        }
    }

    const int gcz = z4 * 4 + cz, gcy = by * 8 + cy, gcx = bx * 8 + cx0;
    const float mv0 = m1[((b * 64 + gcz) * 64 + gcy) * 64 + gcx];
    const float mv1 = m1[((b * 64 + gcz) * 64 + gcy) * 64 + gcx + 1];
    float m = fmaxf(mv0, mv1);
    float r0 = fmaxf(fmaxf(acc[0][0], 0.f) * mv0, fmaxf(acc[1][0], 0.f) * mv1);
    float r1 = fmaxf(fmaxf(acc[0][1], 0.f) * mv0, fmaxf(acc[1][1], 0.f) * mv1);
    float r2 = fmaxf(fmaxf(acc[0][2], 0.f) * mv0, fmaxf(acc[1][2], 0.f) * mv1);
    float r3 = fmaxf(fmaxf(acc[0][3], 0.f) * mv0, fmaxf(acc[1][3], 0.f) * mv1);

    #pragma unroll
    for (int mask = 1; mask <= 2; mask <<= 1) {
        r0 = fmaxf(r0, __shfl_xor(r0, mask));
        r1 = fmaxf(r1, __shfl_xor(r1, mask));
        r2 = fmaxf(r2, __shfl_xor(r2, mask));
        r3 = fmaxf(r3, __shfl_xor(r3, mask));
        m  = fmaxf(m,  __shfl_xor(m,  mask));
    }
    if ((tid & 3) == 0) {
        int pz = z4 * 2 + Z, py = by * 4 + Y, px = bx * 4 + qx;
        int oidx = ((b * 32 + pz) * 32 + py) * 32 + px;
        *(float4*)&h2[oidx * 4] = make_float4(r0, r1, r2, r3);
        m2[oidx] = m;
    }
}

__device__ __forceinline__ float dot4(float4 a, float4 b) {
    return a.x * b.x + a.y * b.y + a.z * b.z + a.w * b.w;
}

// ---------------------------------------------------------------------------
// Kernel C: fused decoder (tconv1 + relu + tconv2 + sigmoid + m2 gating).
// JAX conv_transpose flips the kernel: out[2i+a] = x[i]*W[1-a].
// Weights staged to LDS. Thread = (parent, a, bb); 4 float4 stores each.
// ---------------------------------------------------------------------------
__global__ __launch_bounds__(256)
void k_decoder(const float* __restrict__ h2, const float* __restrict__ m2,
               const float* __restrict__ Wt1, const float* __restrict__ Wt2,
               float* __restrict__ out)
{
    __shared__ float4 w1s[256];   // Wt1: 1024 floats
    __shared__ float4 w2s[32];    // Wt2: 128 floats

    const int tid = threadIdx.x;
    w1s[tid] = ((const float4*)Wt1)[tid];
    if (tid < 32) w2s[tid] = ((const float4*)Wt2)[tid];
    __syncthreads();

    const int T  = blockIdx.x * 256 + tid;          // 0..262143
    const int px = T & 31;
    const int a  = (T >> 5) & 1;
    const int bb = (T >> 6) & 1;
    const int py = (T >> 7) & 31;
    const int pz = (T >> 12) & 31;
    const int b  = T >> 17;
    const int pidx = ((b * 32 + pz) * 32 + py) * 32 + px;

    const float m = m2[pidx];
    const float4 hv = *(const float4*)&h2[pidx * 4];

    const int b0q = ((((1 - a) * 2 + (1 - bb)) * 2) + 1) * 16;  // c=0 -> kc=1
    const int b1q = ((((1 - a) * 2 + (1 - bb)) * 2) + 0) * 16;  // c=1 -> kc=0
    float4 t0q[4], t1q[4];
    #pragma unroll
    for (int q = 0; q < 4; ++q) {
        float4 a0 = w1s[b0q + q],      a1 = w1s[b0q + 4 + q];
        float4 a2 = w1s[b0q + 8 + q],  a3 = w1s[b0q + 12 + q];
        float4 c0 = w1s[b1q + q],      c1 = w1s[b1q + 4 + q];
        float4 c2 = w1s[b1q + 8 + q],  c3 = w1s[b1q + 12 + q];
        float4 s0, s1;
        s0.x = hv.x * a0.x + hv.y * a1.x + hv.z * a2.x + hv.w * a3.x;
        s0.y = hv.x * a0.y + hv.y * a1.y + hv.z * a2.y + hv.w * a3.y;
        s0.z = hv.x * a0.z + hv.y * a1.z + hv.z * a2.z + hv.w * a3.z;
        s0.w = hv.x * a0.w + hv.y * a1.w + hv.z * a2.w + hv.w * a3.w;
        s1.x = hv.x * c0.x + hv.y * c1.x + hv.z * c2.x + hv.w * c3.x;
        s1.y = hv.x * c0.y + hv.y * c1.y + hv.z * c2.y + hv.w * c3.y;
        s1.z = hv.x * c0.z + hv.y * c1.z + hv.z * c2.z + hv.w * c3.z;
        s1.w = hv.x * c0.w + hv.y * c1.w + hv.z * c2.w + hv.w * c3.w;
        t0q[q] = make_float4(fmaxf(s0.x, 0.f), fmaxf(s0.y, 0.f),
                             fmaxf(s0.z, 0.f), fmaxf(s0.w, 0.f));
        t1q[q] = make_float4(fmaxf(s1.x, 0.f), fmaxf(s1.y, 0.f),
                             fmaxf(s1.z, 0.f), fmaxf(s1.w, 0.f));
    }

    #pragma unroll
    for (int e = 0; e < 2; ++e) {
        #pragma unroll
        for (int f = 0; f < 2; ++f) {
            const int d  = 4 * pz + 2 * a + e;
            const int hh = 4 * py + 2 * bb + f;
            const int be = ((1 - e) * 2 + (1 - f)) * 2;
            const float4* wg0 = &w2s[(be + 1) * 4];   // g=0 -> kg=1
            const float4* wg1 = &w2s[(be + 0) * 4];   // g=1 -> kg=0
            float s00 = dot4(t0q[0], wg0[0]) + dot4(t0q[1], wg0[1])
                      + dot4(t0q[2], wg0[2]) + dot4(t0q[3], wg0[3]);
            float s01 = dot4(t0q[0], wg1[0]) + dot4(t0q[1], wg1[1])
                      + dot4(t0q[2], wg1[2]) + dot4(t0q[3], wg1[3]);
            float s10 = dot4(t1q[0], wg0[0]) + dot4(t1q[1], wg0[1])
                      + dot4(t1q[2], wg0[2]) + dot4(t1q[3], wg0[3]);
            float s11 = dot4(t1q[0], wg1[0]) + dot4(t1q[1], wg1[1])
                      + dot4(t1q[2], wg1[2]) + dot4(t1q[3], wg1[3]);
            float4 o;
            o.x = m / (1.f + __expf(-s00));
            o.y = m / (1.f + __expf(-s01));
            o.z = m / (1.f + __expf(-s10));
            o.w = m / (1.f + __expf(-s11));
            *(float4*)&out[((b * G + d) * G + hh) * G + 4 * px] = o;
        }
    }
}

extern "C" void kernel_launch(void* const* d_in, const int* in_sizes, int n_in,
                              void* d_out, int out_size, void* d_ws, size_t ws_size,
                              hipStream_t stream) {
    (void)in_sizes; (void)n_in; (void)out_size; (void)ws_size;
    const float* x   = (const float*)d_in[0];
    const float* W1  = (const float*)d_in[1];
    const float* W2  = (const float*)d_in[2];
    const float* Wt1 = (const float*)d_in[3];
    const float* Wt2 = (const float*)d_in[4];
    const int*   occ = (const int*)d_in[5];
    float* out = (float*)d_out;

    char* ws = (char*)d_ws;
    __half* h1p = (__half*)ws;                                  // 16 MB
    float*  m1  = (float*)(ws + 8388608ull * sizeof(__half));   // 2 MB
    float*  h2  = m1 + 524288;                                  // 1 MB
    float*  m2v = h2 + 262144;                                  // 256 KB
    __half* w2h = (__half*)(m2v + 65536);                       // 3456 B
    __half* w1h = w2h + 1728;                                   // 864 B

    k_prep<<<dim3(4), dim3(256), 0, stream>>>(W1, W2, w1h, w2h);
    k_conv1_pool<<<dim3(8, 8, 32), dim3(256), 0, stream>>>(x, occ, (const h2_t*)w1h, h1p, m1);
    k_conv2_pool<<<dim3(8, 8, 32), dim3(128), 0, stream>>>(h1p, m1, (const h2_t*)w2h, h2, m2v);
    k_decoder<<<dim3(1024), dim3(256), 0, stream>>>(h2, m2v, Wt1, Wt2, out);
}

// Round 9
// 166.305 us; speedup vs baseline: 1.8347x; 1.0129x over previous
//
#include <hip/hip_runtime.h>
#include <hip/hip_fp16.h>

#define G 128

typedef _Float16 h2_t __attribute__((ext_vector_type(2)));

union U16 { uint4 u; h2_t h2[4]; };
union HV  { uint4 u; h2_t h2[4]; };

__device__ __forceinline__ float dot2f(h2_t a, h2_t b, float c) {
#if __has_builtin(__builtin_amdgcn_fdot2)
    return __builtin_amdgcn_fdot2(a, b, c, false);
#else
    return c + (float)a.x * (float)b.x + (float)a.y * (float)b.y;
#endif
}

__device__ __forceinline__ h2_t h2max(h2_t a, h2_t b) {
#if __has_builtin(__builtin_elementwise_max)
    return __builtin_elementwise_max(a, b);
#else
    h2_t r;
    r.x = a.x > b.x ? a.x : b.x;
    r.y = a.y > b.y ? a.y : b.y;
    return r;
#endif
}

__device__ __forceinline__ float dot4(float4 a, float4 b) {
    return a.x * b.x + a.y * b.y + a.z * b.z + a.w * b.w;
}

// ---------------------------------------------------------------------------
// Kernel P: pack weights to fp16 half2 (global, read via scalar loads later).
//  w1h[tap*8 + p]       = (W1[tap][2p],   W1[tap][2p+1])          216 h2
//  w2h[t*32 + co*8 + p] = (W2[t][2p][co], W2[t][2p+1][co])        864 h2
// ---------------------------------------------------------------------------
__global__ void k_prep(const float* __restrict__ W1, const float* __restrict__ W2,
                       __half* __restrict__ w1h, __half* __restrict__ w2h)
{
    int i = blockIdx.x * 256 + threadIdx.x;
    if (i < 216) {
        int tap = i >> 3, p = i & 7;
        w1h[2 * i]     = __float2half(W1[tap * 16 + 2 * p]);
        w1h[2 * i + 1] = __float2half(W1[tap * 16 + 2 * p + 1]);
    }
    if (i < 864) {
        int t = i >> 5, r = i & 31, co = r >> 3, p = r & 7;
        w2h[2 * i]     = __float2half(W2[t * 64 + (2 * p) * 4 + co]);
        w2h[2 * i + 1] = __float2half(W2[t * 64 + (2 * p + 1) * 4 + co]);
    }
}

// ---------------------------------------------------------------------------
// Kernel A: fused conv1 (3x3x3, 1->16, SAME) + relu + m0-mask + 2x2x2 maxpool.
// Identical to R8 except __launch_bounds__(256,2): R8's (256,4) produced
// VGPR=20, which serializes the 26-load staging pipeline (each oc/xv pair
// must stay resident until consumed). Let the allocator use ~128.
// ---------------------------------------------------------------------------
__global__ __launch_bounds__(256, 2)
void k_conv1_pool(const float* __restrict__ x, const int* __restrict__ occ,
                  const h2_t* __restrict__ w1h,
                  __half* __restrict__ h1p, float* __restrict__ m1)
{
    __shared__ _Float16      sx[10 * 18 * 18];   // [z][y][x]
    __shared__ unsigned char sm[10 * 18 * 18];

    const int bx = blockIdx.x, by = blockIdx.y;
    const int b  = blockIdx.z >> 4, zt = blockIdx.z & 15;
    const int tid = threadIdx.x;

    const int z0 = zt * 8 - 1, y0 = by * 16 - 1, x0 = bx * 16 - 1;
    const int base_b = b * G * G * G;

    #pragma unroll
    for (int r = 0; r < 13; ++r) {
        int i = r * 256 + tid;
        if (i < 3240) {
            int lz = i / 324, rr = i - lz * 324;
            int ly = rr / 18, lx = rr - ly * 18;
            int gz = z0 + lz, gy = y0 + ly, gx = x0 + lx;
            bool inb = (unsigned)gz < 128u && (unsigned)gy < 128u &&
                       (unsigned)gx < 128u;
            int oc = 1; float xv = 0.f;
            if (inb) {                 // two independent loads, both in flight
                int gi = base_b + (gz * G + gy) * G + gx;
                oc = occ[gi];
                xv = x[gi];
            }
            bool mm = inb && (oc == 0);
            sx[i] = mm ? (_Float16)xv : (_Float16)0.f;
            sm[i] = mm ? 1 : 0;
        }
    }
    __syncthreads();

    const int tx = tid & 7, ty = (tid >> 3) & 7, tz = tid >> 6;

    const h2_t zero = (h2_t)(_Float16)0.f;
    h2_t best[8];
    #pragma unroll
    for (int c = 0; c < 8; ++c) best[c] = zero;
    int anym = 0;

    #pragma unroll
    for (int pos = 0; pos < 8; ++pos) {
        const int dz = pos >> 2, dy = (pos >> 1) & 1, dx = pos & 1;
        const int cz = 2 * tz + dz, cy = 2 * ty + dy, cx = 2 * tx + dx;
        const int cb = (cz + 1) * 324 + (cy + 1) * 18 + (cx + 1);
        if (sm[cb]) {
            anym = 1;
            h2_t acc[8];
            #pragma unroll
            for (int c = 0; c < 8; ++c) acc[c] = zero;
            #pragma unroll
            for (int kz = 0; kz < 3; ++kz)
            #pragma unroll
            for (int ky = 0; ky < 3; ++ky)
            #pragma unroll
            for (int kx = 0; kx < 3; ++kx) {
                _Float16 v = sx[cb + (kz - 1) * 324 + (ky - 1) * 18 + (kx - 1)];
                h2_t v2 = {v, v};
                const h2_t* w = &w1h[((kz * 3 + ky) * 3 + kx) * 8];   // uniform
                #pragma unroll
                for (int c = 0; c < 8; ++c) acc[c] = v2 * w[c] + acc[c];
            }
            #pragma unroll
            for (int c = 0; c < 8; ++c) best[c] = h2max(best[c], h2max(acc[c], zero));
        }
    }

    const int pz = zt * 4 + tz, py = by * 8 + ty, px = bx * 8 + tx;
    const int vidx = ((b * 64 + pz) * 64 + py) * 64 + px;
    HV p0, p1;
    #pragma unroll
    for (int c = 0; c < 4; ++c) { p0.h2[c] = best[c]; p1.h2[c] = best[4 + c]; }
    uint4* o = (uint4*)&h1p[(size_t)vidx * 16];
    o[0] = p0.u;
    o[1] = p1.u;
    m1[vidx] = anym ? 1.f : 0.f;
}

// ---------------------------------------------------------------------------
// Kernel B: fused conv2 (3x3x3, 16->4) + relu + m1-mask + pool + FULL DECODER
// (tconv1 4->16 + relu, tconv2 16->1 + sigmoid, m2 gating).
// 256 thr, conv region 8^3 -> 64 parents -> exactly 256 decoder threads
// (parent, a, bb). Pool leaders pass (h2,m2) via LDS; decoder weights staged
// to LDS (Wt1 = 128 float4 — NOT 256; prior rounds over-read by 2KB).
// Eliminates the separate decoder dispatch and the h2/m2 global round-trip.
// conv2 math: fp16 dot2, weights from global w2h (scalar loads, uniform).
// Grid (8,8,16). LDS ~24KB -> 6 blk/CU (24 waves).
// ---------------------------------------------------------------------------
__global__ __launch_bounds__(256)
void k_conv2_dec(const __half* __restrict__ h1p, const float* __restrict__ m1,
                 const h2_t* __restrict__ w2h,
                 const float* __restrict__ Wt1, const float* __restrict__ Wt2,
                 float* __restrict__ out)
{
    __shared__ uint4  tile[1100];   // 10*10*11 voxels, 8ch fp16 = 17.6 KB
    __shared__ float4 wt1[128];     // Wt1: 512 floats
    __shared__ float4 wt2[32];      // Wt2: 128 floats
    __shared__ float4 sh_h[64];     // pooled h2 per parent
    __shared__ float  sh_m[64];     // pooled m2 per parent

    const int bx = blockIdx.x, by = blockIdx.y;
    const int b  = blockIdx.z >> 3, bz = blockIdx.z & 7;
    const int tid = threadIdx.x;

    if (tid < 128) wt1[tid] = ((const float4*)Wt1)[tid];
    if (tid < 32)  wt2[tid] = ((const float4*)Wt2)[tid];

    const int z0 = bz * 8 - 1, y0 = by * 8 - 1, x0 = bx * 8 - 1;

    const int dy = tid & 1, dz = (tid >> 1) & 1;
    const int qx = (tid >> 2) & 3, Y = (tid >> 4) & 3, Z = (tid >> 6) & 3;
    const int cx0 = 2 * qx, cy = 2 * Y + dy, cz = 2 * Z + dz;

    float acc[2][4] = {{0.f, 0.f, 0.f, 0.f}, {0.f, 0.f, 0.f, 0.f}};

    for (int h = 0; h < 2; ++h) {
        if (h) __syncthreads();
        #pragma unroll
        for (int it = 0; it < 5; ++it) {
            int g = it * 256 + tid;
            if (g < 1100) {
                int z = g / 110, r = g - z * 110, y = r / 11, xx = r - y * 11;
                int gz = z0 + z, gy = y0 + y, gx = x0 + xx;
                uint4 a = make_uint4(0u, 0u, 0u, 0u);
                if ((unsigned)gz < 64u && (unsigned)gy < 64u && (unsigned)gx < 64u)
                    a = ((const uint4*)&h1p[(size_t)(((b * 64 + gz) * 64 + gy) * 64 + gx) * 16])[h];
                tile[g] = a;
            }
        }
        __syncthreads();

        #pragma unroll
        for (int kz = 0; kz < 3; ++kz)
        #pragma unroll
        for (int ky = 0; ky < 3; ++ky) {
            const int rb = (cz + kz) * 110 + (cy + ky) * 11 + cx0;
            h2_t hp[4][4];
            #pragma unroll
            for (int xi = 0; xi < 4; ++xi) {
                U16 a; a.u = tile[rb + xi];
                #pragma unroll
                for (int p = 0; p < 4; ++p) hp[xi][p] = a.h2[p];
            }
            const int t3 = (kz * 3 + ky) * 3;
            #pragma unroll
            for (int kx = 0; kx < 3; ++kx) {
                const h2_t* w = w2h + (t3 + kx) * 32 + 4 * h;   // uniform -> s_load
                #pragma unroll
                for (int j = 0; j < 2; ++j) {
                    #pragma unroll
                    for (int co = 0; co < 4; ++co) {
                        float a = acc[j][co];
                        #pragma unroll
                        for (int p = 0; p < 4; ++p)
                            a = dot2f(hp[kx + j][p], w[co * 8 + p], a);
                        acc[j][co] = a;
                    }
                }
            }
        }
    }

    // ---- mask + relu + pool ----
    const int gcz = bz * 8 + cz, gcy = by * 8 + cy, gcx = bx * 8 + cx0;
    const float mv0 = m1[((b * 64 + gcz) * 64 + gcy) * 64 + gcx];
    const float mv1 = m1[((b * 64 + gcz) * 64 + gcy) * 64 + gcx + 1];
    float m = fmaxf(mv0, mv1);
    float r0 = fmaxf(fmaxf(acc[0][0], 0.f) * mv0, fmaxf(acc[1][0], 0.f) * mv1);
    float r1 = fmaxf(fmaxf(acc[0][1], 0.f) * mv0, fmaxf(acc[1][1], 0.f) * mv1);
    float r2 = fmaxf(fmaxf(acc[0][2], 0.f) * mv0, fmaxf(acc[1][2], 0.f) * mv1);
    float r3 = fmaxf(fmaxf(acc[0][3], 0.f) * mv0, fmaxf(acc[1][3], 0.f) * mv1);

    #pragma unroll
    for (int mask = 1; mask <= 2; mask <<= 1) {
        r0 = fmaxf(r0, __shfl_xor(r0, mask));
        r1 = fmaxf(r1, __shfl_xor(r1, mask));
        r2 = fmaxf(r2, __shfl_xor(r2, mask));
        r3 = fmaxf(r3, __shfl_xor(r3, mask));
        m  = fmaxf(m,  __shfl_xor(m,  mask));
    }
    if ((tid & 3) == 0) {
        int p = Z * 16 + Y * 4 + qx;
        sh_h[p] = make_float4(r0, r1, r2, r3);
        sh_m[p] = m;
    }
    __syncthreads();

    // ---- decoder phase: thread = (parent p, a, bb) ----
    {
        const int p  = tid >> 2;
        const int a  = (tid >> 1) & 1;
        const int bb = tid & 1;
        const int pZ = p >> 4, pY = (p >> 2) & 3, pq = p & 3;
        const int pz = bz * 4 + pZ, py = by * 4 + pY, pxq = bx * 4 + pq;

        const float mm = sh_m[p];
        const float4 hv = sh_h[p];

        const int b0q = ((((1 - a) * 2 + (1 - bb)) * 2) + 1) * 16;  // c=0 -> kc=1
        const int b1q = ((((1 - a) * 2 + (1 - bb)) * 2) + 0) * 16;  // c=1 -> kc=0
        float4 t0q[4], t1q[4];
        #pragma unroll
        for (int q = 0; q < 4; ++q) {
            float4 a0 = wt1[b0q + q],      a1 = wt1[b0q + 4 + q];
            float4 a2 = wt1[b0q + 8 + q],  a3 = wt1[b0q + 12 + q];
            float4 c0 = wt1[b1q + q],      c1 = wt1[b1q + 4 + q];
            float4 c2 = wt1[b1q + 8 + q],  c3 = wt1[b1q + 12 + q];
            float4 s0, s1;
            s0.x = hv.x * a0.x + hv.y * a1.x + hv.z * a2.x + hv.w * a3.x;
            s0.y = hv.x * a0.y + hv.y * a1.y + hv.z * a2.y + hv.w * a3.y;
            s0.z = hv.x * a0.z + hv.y * a1.z + hv.z * a2.z + hv.w * a3.z;
            s0.w = hv.x * a0.w + hv.y * a1.w + hv.z * a2.w + hv.w * a3.w;
            s1.x = hv.x * c0.x + hv.y * c1.x + hv.z * c2.x + hv.w * c3.x;
            s1.y = hv.x * c0.y + hv.y * c1.y + hv.z * c2.y + hv.w * c3.y;
            s1.z = hv.x * c0.z + hv.y * c1.z + hv.z * c2.z + hv.w * c3.z;
            s1.w = hv.x * c0.w + hv.y * c1.w + hv.z * c2.w + hv.w * c3.w;
            t0q[q] = make_float4(fmaxf(s0.x, 0.f), fmaxf(s0.y, 0.f),
                                 fmaxf(s0.z, 0.f), fmaxf(s0.w, 0.f));
            t1q[q] = make_float4(fmaxf(s1.x, 0.f), fmaxf(s1.y, 0.f),
                                 fmaxf(s1.z, 0.f), fmaxf(s1.w, 0.f));
        }

        #pragma unroll
        for (int e = 0; e < 2; ++e) {
            #pragma unroll
            for (int f = 0; f < 2; ++f) {
                const int d  = 4 * pz + 2 * a + e;
                const int hh = 4 * py + 2 * bb + f;
                const int be = ((1 - e) * 2 + (1 - f)) * 2;
                const float4* wg0 = &wt2[(be + 1) * 4];   // g=0 -> kg=1
                const float4* wg1 = &wt2[(be + 0) * 4];   // g=1 -> kg=0
                float s00 = dot4(t0q[0], wg0[0]) + dot4(t0q[1], wg0[1])
                          + dot4(t0q[2], wg0[2]) + dot4(t0q[3], wg0[3]);
                float s01 = dot4(t0q[0], wg1[0]) + dot4(t0q[1], wg1[1])
                          + dot4(t0q[2], wg1[2]) + dot4(t0q[3], wg1[3]);
                float s10 = dot4(t1q[0], wg0[0]) + dot4(t1q[1], wg0[1])
                          + dot4(t1q[2], wg0[2]) + dot4(t1q[3], wg0[3]);
                float s11 = dot4(t1q[0], wg1[0]) + dot4(t1q[1], wg1[1])
                          + dot4(t1q[2], wg1[2]) + dot4(t1q[3], wg1[3]);
                float4 o;
                o.x = mm / (1.f + __expf(-s00));
                o.y = mm / (1.f + __expf(-s01));
                o.z = mm / (1.f + __expf(-s10));
                o.w = mm / (1.f + __expf(-s11));
                *(float4*)&out[((b * G + d) * G + hh) * G + 4 * pxq] = o;
            }
        }
    }
}

extern "C" void kernel_launch(void* const* d_in, const int* in_sizes, int n_in,
                              void* d_out, int out_size, void* d_ws, size_t ws_size,
                              hipStream_t stream) {
    (void)in_sizes; (void)n_in; (void)out_size; (void)ws_size;
    const float* x   = (const float*)d_in[0];
    const float* W1  = (const float*)d_in[1];
    const float* W2  = (const float*)d_in[2];
    const float* Wt1 = (const float*)d_in[3];
    const float* Wt2 = (const float*)d_in[4];
    const int*   occ = (const int*)d_in[5];
    float* out = (float*)d_out;

    char* ws = (char*)d_ws;
    __half* h1p = (__half*)ws;                                  // 16 MB
    float*  m1  = (float*)(ws + 8388608ull * sizeof(__half));   // 2 MB
    __half* w2h = (__half*)(m1 + 524288);                       // 3456 B
    __half* w1h = w2h + 1728;                                   // 864 B

    k_prep<<<dim3(4), dim3(256), 0, stream>>>(W1, W2, w1h, w2h);
    k_conv1_pool<<<dim3(8, 8, 32), dim3(256), 0, stream>>>(x, occ, (const h2_t*)w1h, h1p, m1);
    k_conv2_dec<<<dim3(8, 8, 16), dim3(256), 0, stream>>>(h1p, m1, (const h2_t*)w2h, Wt1, Wt2, out);
}